// Round 1
// 530.770 us; speedup vs baseline: 1.3599x; 1.3599x over previous
//
#include <hip/hip_runtime.h>
#include <math.h>

// WindAdvectionBlock: B=8, C=256, H=W=128, mid=64
// compress(1x1,MFMA) -> off1+gelu -> off2 -> deform(MFMA, coalesced gather,
// XCD-swizzled) -> [analytic GN stats, 2-stage non-atomic] -> final(MFMA
// expand+GN+gelu+residual)

#define BB 8
#define CC 256
#define HW 16384
#define MID 64

typedef __attribute__((ext_vector_type(8))) short bf16x8;
typedef __attribute__((ext_vector_type(4))) float f32x4;

__device__ __forceinline__ float gelu_f(float v){
  return 0.5f*v*(1.0f + erff(v*0.7071067811865476f));
}
__device__ __forceinline__ unsigned f2bf(float f){
  union { float f; unsigned u; } v; v.f = f;
  unsigned u = v.u;
  u += 0x7fff + ((u >> 16) & 1);   // RNE
  return (u >> 16);
}

// ---- prep: bt bf16 [9][64o][64c] from dw [64o][64c][9]; cwb bf16 [64o][256c];
//            ewb bf16 [256o][64c]
__global__ void k_prep(const float* __restrict__ dw, const float* __restrict__ cw,
                       const float* __restrict__ ew, ushort* __restrict__ bt,
                       ushort* __restrict__ cwb, ushort* __restrict__ ewb){
  int i = blockIdx.x*256 + threadIdx.x;
  if (i < 36864){
    int k = i >> 12, r = i & 4095;
    int o = r >> 6, c = r & 63;
    bt[i] = (ushort)f2bf(dw[(o*64+c)*9 + k]);
  }
  int j = i - 36864;
  if (j >= 0 && j < 16384) cwb[j] = (ushort)f2bf(cw[j]);
  int l = i - 53248;
  if (l >= 0 && l < 16384) ewb[l] = (ushort)f2bf(ew[l]);
}

// ---- compress 1x1 via MFMA: feat NCHW -> x NHWC [b][p][64]
// block = 128 px; K-loop 4 tiles of 64 ch; A staged via register transpose.
__global__ __launch_bounds__(256) void k_compress(const float* __restrict__ feat,
    const ushort* __restrict__ cwb, const float* __restrict__ cb, float* __restrict__ xo){
  __shared__ ushort A[128*64];           // 16 KB, [px][64c] bf16, 16B chunks xor px&7
  int t = threadIdx.x;
  int b = blockIdx.y, p0 = blockIdx.x*128;
  int lane = t & 63, w = t >> 6, ln = lane & 15, qd = lane >> 4;
  int n = (w<<4) + ln;                   // out channel
  int cg = t >> 4, pxg = t & 15;         // staging: 4-ch group, 8-px group
  f32x4 acc[8];
  #pragma unroll
  for (int pt=0;pt<8;pt++) acc[pt] = (f32x4){0.f,0.f,0.f,0.f};
  for (int kt=0;kt<4;kt++){
    // load 4 channels x 8 px into regs
    const float* fb = feat + ((size_t)(b*CC + kt*64 + cg*4))*HW + p0 + pxg*8;
    float v[4][8];
    #pragma unroll
    for (int i=0;i<4;i++){
      *(float4*)&v[i][0] = *(const float4*)(fb + (size_t)i*HW);
      *(float4*)&v[i][4] = *(const float4*)(fb + (size_t)i*HW + 4);
    }
    __syncthreads();                     // prev tile's readers done
    #pragma unroll
    for (int j=0;j<8;j++){
      int px = pxg*8 + j;
      unsigned lo = f2bf(v[0][j]) | (f2bf(v[1][j])<<16);
      unsigned hi = f2bf(v[2][j]) | (f2bf(v[3][j])<<16);
      int chunk = (cg>>1) ^ (px&7);
      *(uint2*)((char*)A + px*128 + chunk*16 + (cg&1)*8) = make_uint2(lo,hi);
    }
    __syncthreads();
    const ushort* wb = cwb + (size_t)n*256 + kt*64 + (qd<<3);
    bf16x8 b0 = *(const bf16x8*)wb;
    bf16x8 b1 = *(const bf16x8*)(wb + 32);
    #pragma unroll
    for (int pt=0;pt<8;pt++){
      int m = (pt<<4) + ln;
      int ch0 = qd ^ (m&7), ch1 = (4+qd) ^ (m&7);
      bf16x8 a0 = *(bf16x8*)(A + (m<<6) + (ch0<<3));
      acc[pt] = __builtin_amdgcn_mfma_f32_16x16x32_bf16(a0, b0, acc[pt], 0,0,0);
      bf16x8 a1 = *(bf16x8*)(A + (m<<6) + (ch1<<3));
      acc[pt] = __builtin_amdgcn_mfma_f32_16x16x32_bf16(a1, b1, acc[pt], 0,0,0);
    }
  }
  float bias = cb[n];
  float* xp = xo + ((size_t)(b*HW + p0))*64 + n;
  #pragma unroll
  for (int pt=0;pt<8;pt++){
    #pragma unroll
    for (int rg=0;rg<4;rg++){
      int px = (pt<<4) + (qd<<2) + rg;
      xp[(size_t)px*64] = acc[pt][rg] + bias;
    }
  }
}

// ---- off1: wind [b][2][H][W] -> h NHWC [b][p][32], conv3x3 pad1 + gelu
__global__ __launch_bounds__(256) void k_off1(const float* __restrict__ wind,
    const float* __restrict__ w1, const float* __restrict__ b1, float* __restrict__ ho){
  __shared__ float wl[576];
  int t=threadIdx.x;
  for (int i=t;i<576;i+=256) wl[i]=w1[i];
  __syncthreads();
  int b=blockIdx.y; int p=blockIdx.x*256+t;
  int y=p>>7, x=p&127;
  float tap[18];
  #pragma unroll
  for (int c=0;c<2;c++){
    #pragma unroll
    for (int ki=0;ki<3;ki++){
      #pragma unroll
      for (int kj=0;kj<3;kj++){
        int yy=y+ki-1, xx=x+kj-1;
        float v=0.f;
        if ((unsigned)yy<128u && (unsigned)xx<128u)
          v = wind[((size_t)b*2+c)*HW + (yy<<7)+xx];
        tap[c*9+ki*3+kj]=v;
      }
    }
  }
  float outv[32];
  #pragma unroll
  for (int o=0;o<32;o++){
    float a=b1[o];
    #pragma unroll
    for (int i=0;i<18;i++) a += tap[i]*wl[o*18+i];
    outv[o]=gelu_f(a);
  }
  float* hp = ho + ((size_t)(b*HW+p))*32;
  #pragma unroll
  for (int o=0;o<32;o+=4) *(float4*)(hp+o)=make_float4(outv[o],outv[o+1],outv[o+2],outv[o+3]);
}

// ---- off2: h NHWC [b][p][32] -> offsets NHWC [b][p][18], conv3x3 pad1
__global__ __launch_bounds__(256) void k_off2(const float* __restrict__ h,
    const float* __restrict__ w2, const float* __restrict__ b2, float* __restrict__ oo){
  __shared__ float wl[9*18*32];
  int t=threadIdx.x;
  for (int i=t;i<5184;i+=256){
    int k=i/576; int r=i-k*576; int o=r>>5; int c=r&31;
    wl[i] = w2[(o*32+c)*9+k];
  }
  __syncthreads();
  int b=blockIdx.y; int p=blockIdx.x*256+t;
  int y=p>>7, x=p&127;
  float acc[18];
  #pragma unroll
  for (int o=0;o<18;o++) acc[o]=b2[o];
  for (int ki=0;ki<3;ki++){
    for (int kj=0;kj<3;kj++){
      int k = ki*3+kj;
      int yy=y+ki-1, xx=x+kj-1;
      float4 hv[8];
      if ((unsigned)yy<128u && (unsigned)xx<128u){
        const float* hp = h + ((size_t)(b*HW) + (yy<<7)+xx)*32;
        #pragma unroll
        for (int q=0;q<8;q++) hv[q]=*(const float4*)(hp+q*4);
      } else {
        #pragma unroll
        for (int q=0;q<8;q++) hv[q]=make_float4(0.f,0.f,0.f,0.f);
      }
      const float* wk = &wl[k*576];
      #pragma unroll
      for (int o=0;o<18;o++){
        float a=acc[o];
        #pragma unroll
        for (int q=0;q<8;q++){
          float4 w4 = *(const float4*)(wk + o*32 + q*4);
          a += hv[q].x*w4.x + hv[q].y*w4.y + hv[q].z*w4.z + hv[q].w*w4.w;
        }
        acc[o]=a;
      }
    }
  }
  float* op = oo + ((size_t)(b*HW+p))*18;
  #pragma unroll
  for (int o=0;o<18;o+=2) *(float2*)(op+o)=make_float2(acc[o],acc[o+1]);
}

// ---- deform conv MFMA, coalesced gather.
// Grid 1024 linear: b = blk&7 (XCD locality), r = blk>>3.
__global__ __launch_bounds__(256) void k_deform(
    const float* __restrict__ x, const float* __restrict__ off,
    const ushort* __restrict__ bt, const float* __restrict__ db,
    float* __restrict__ yo){
  __shared__ ushort A[128*64];           // 16 KB
  __shared__ float offs[128*18];         // 9 KB
  int t = threadIdx.x;
  int blk = blockIdx.x;
  int b = blk & 7, r = blk >> 3;
  int p0 = r*128;
  const float* offg = off + ((size_t)(b*HW + p0))*18;
  for (int i=t;i<576;i+=256)
    *(float4*)(offs + i*4) = *(const float4*)(offg + i*4);
  __syncthreads();
  int lane = t & 63, w = t >> 6, ln = lane & 15, qd = lane >> 4;
  int n = (w<<4) + ln;
  const float* xb = x + (size_t)b*HW*64;
  f32x4 acc[8];
  #pragma unroll
  for (int pt=0;pt<8;pt++) acc[pt] = (f32x4){0.f,0.f,0.f,0.f};

  for (int k=0;k<9;k++){
    int ki = k/3, kj = k - ki*3;
    const ushort* btk = bt + (size_t)(((k<<6) + n)<<6) + (qd<<3);
    bf16x8 bf0 = *(const bf16x8*)btk;
    bf16x8 bf1 = *(const bf16x8*)(btk + 32);
    __syncthreads();                     // prev tap's MFMA reads done
    #pragma unroll
    for (int pp=0;pp<8;pp++){
      int p = (w<<5) + (pp<<2) + qd;     // pixel (x-coord) 0..127
      float2 dd = *(const float2*)(offs + p*18 + 2*k);
      float py  = dd.x + (float)(r + ki - 1);
      float pxs = dd.y + (float)(p + kj - 1);
      float y0f = floorf(py), x0f = floorf(pxs);
      float fy = py - y0f, fx = pxs - x0f;
      int y0 = (int)y0f, x0 = (int)x0f;
      float w00=(1.f-fy)*(1.f-fx), w01=(1.f-fy)*fx, w10=fy*(1.f-fx), w11=fy*fx;
      bool v0=((unsigned)y0<128u), v1=((unsigned)(y0+1)<128u);
      bool u0=((unsigned)x0<128u), u1=((unsigned)(x0+1)<128u);
      w00 = (v0&&u0)? w00 : 0.f;  w01 = (v0&&u1)? w01 : 0.f;
      w10 = (v1&&u0)? w10 : 0.f;  w11 = (v1&&u1)? w11 : 0.f;
      int y0c = min(max(y0,0),127), y1c = min(max(y0+1,0),127);
      int x0c = min(max(x0,0),127), x1c = min(max(x0+1,0),127);
      int cofs = (ln<<2);
      const float4* r00 = (const float4*)(xb + (size_t)y0c*8192 + x0c*64 + cofs);
      const float4* r01 = (const float4*)(xb + (size_t)y0c*8192 + x1c*64 + cofs);
      const float4* r10 = (const float4*)(xb + (size_t)y1c*8192 + x0c*64 + cofs);
      const float4* r11 = (const float4*)(xb + (size_t)y1c*8192 + x1c*64 + cofs);
      float4 a00=*r00, a01=*r01, a10=*r10, a11=*r11;
      float4 s;
      s.x = a00.x*w00 + a01.x*w01 + a10.x*w10 + a11.x*w11;
      s.y = a00.y*w00 + a01.y*w01 + a10.y*w10 + a11.y*w11;
      s.z = a00.z*w00 + a01.z*w01 + a10.z*w10 + a11.z*w11;
      s.w = a00.w*w00 + a01.w*w01 + a10.w*w10 + a11.w*w11;
      unsigned lo = f2bf(s.x) | (f2bf(s.y)<<16);
      unsigned hi = f2bf(s.z) | (f2bf(s.w)<<16);
      int chunk = (ln>>1) ^ (p&7);
      *(uint2*)((char*)A + p*128 + chunk*16 + (ln&1)*8) = make_uint2(lo,hi);
    }
    __syncthreads();                     // A tile ready
    #pragma unroll
    for (int pt=0;pt<8;pt++){
      int m = (pt<<4) + ln;
      int ch0 = qd ^ (m&7), ch1 = (4+qd) ^ (m&7);
      bf16x8 a0 = *(bf16x8*)(A + (m<<6) + (ch0<<3));
      acc[pt] = __builtin_amdgcn_mfma_f32_16x16x32_bf16(a0, bf0, acc[pt], 0,0,0);
      bf16x8 a1 = *(bf16x8*)(A + (m<<6) + (ch1<<3));
      acc[pt] = __builtin_amdgcn_mfma_f32_16x16x32_bf16(a1, bf1, acc[pt], 0,0,0);
    }
  }
  float bias = db[n];
  float* yp = yo + ((size_t)(b*HW + p0))*64 + n;
  #pragma unroll
  for (int pt=0;pt<8;pt++){
    #pragma unroll
    for (int rg=0;rg<4;rg++){
      int px = (pt<<4) + (qd<<2) + rg;
      yp[(size_t)px*64] = acc[pt][rg] + bias;
    }
  }
}

// ---- stats stage A: per-block partial Y2 (64x64) + ybar (64), NO atomics.
// Thread t owns a 4x4 output tile: ib = t&15 (rows), jb = t>>4 (cols).
// 2 x ds_read_b128 per pixel per thread (was 5 LDS instrs with the 1x16 layout).
__global__ __launch_bounds__(256) void k_stats(const float* __restrict__ y,
    float* __restrict__ partY2, float* __restrict__ partYb){
  __shared__ float yt[128*64];
  int t=threadIdx.x; int b=blockIdx.y; int r=blockIdx.x;
  const float* yp = y + ((size_t)(b*HW) + (size_t)r*128)*64;
  for (int i=t*4;i<8192;i+=1024) *(float4*)&yt[i]=*(const float4*)(yp+i);
  __syncthreads();
  int ib = t & 15, jb = t >> 4;
  float acc[4][4];
  #pragma unroll
  for (int a=0;a<4;a++)
    #pragma unroll
    for (int c=0;c<4;c++) acc[a][c]=0.f;
  for (int p=0;p<128;p++){
    float4 vi = *(const float4*)&yt[(p<<6)+(ib<<2)];
    float4 vj = *(const float4*)&yt[(p<<6)+(jb<<2)];
    float fi[4]={vi.x,vi.y,vi.z,vi.w};
    float fj[4]={vj.x,vj.y,vj.z,vj.w};
    #pragma unroll
    for (int a=0;a<4;a++)
      #pragma unroll
      for (int c=0;c<4;c++) acc[a][c] += fi[a]*fj[c];
  }
  float* pb = partY2 + ((size_t)(b*128+r))*4096;
  #pragma unroll
  for (int a=0;a<4;a++)
    *(float4*)(pb + (ib*4+a)*64 + jb*4) =
        make_float4(acc[a][0],acc[a][1],acc[a][2],acc[a][3]);
  if (t < 64){
    float s=0.f;
    for (int p=0;p<128;p++) s += yt[(p<<6)+t];
    partYb[(size_t)(b*128+r)*64 + t] = s;
  }
}

// ---- stats stage B: fold 128 partials per batch into Y2 / ybar (coalesced).
__global__ __launch_bounds__(256) void k_reduce(const float* __restrict__ partY2,
    const float* __restrict__ partYb, float* __restrict__ Y2,
    float* __restrict__ ybar){
  int t=threadIdx.x; int b=blockIdx.y;
  if (blockIdx.x < 4){
    int e = (blockIdx.x*256 + t)*4;
    const float* p = partY2 + ((size_t)b*128)*4096 + e;
    float4 s=make_float4(0.f,0.f,0.f,0.f);
    for (int r=0;r<128;r++){
      float4 v=*(const float4*)(p+(size_t)r*4096);
      s.x+=v.x; s.y+=v.y; s.z+=v.z; s.w+=v.w;
    }
    *(float4*)(Y2+((size_t)b<<12)+e)=s;
  } else if (t < 16){
    int e = t*4;
    const float* p = partYb + (size_t)b*8192 + e;
    float4 s=make_float4(0.f,0.f,0.f,0.f);
    for (int r=0;r<128;r++){
      float4 v=*(const float4*)(p+r*64);
      s.x+=v.x; s.y+=v.y; s.z+=v.z; s.w+=v.w;
    }
    *(float4*)(ybar+(b<<6)+e)=s;
  }
}

// ---- analytic GN stats per (b,g): mu, rstd of z = expand(y)
__global__ __launch_bounds__(256) void k_gn(const float* __restrict__ Y2,
    const float* __restrict__ ybar, const float* __restrict__ ew,
    const float* __restrict__ eb, float* __restrict__ stats){
  __shared__ float wsm[64*65];
  __shared__ float red[512];
  int t=threadIdx.x;
  int bg=blockIdx.x, b=bg>>2, g=bg&3;
  for (int i=t;i<4096;i+=256){
    int c=i>>6, m=i&63;
    wsm[c*65+m] = ew[(((size_t)g<<6)+c)*64 + m];
  }
  __syncthreads();
  int c = t&63, qm = t>>6;
  const float* wv = &wsm[c*65];
  const float* Y2b = Y2 + ((size_t)b<<12);
  const float* yb = ybar + (b<<6);
  float q=0.f, sbp=0.f;
  for (int m=qm*16; m<qm*16+16; m++){
    const float* row = Y2b + (m<<6);
    float ym=0.f;
    for (int nn=0;nn<64;nn+=4){
      float4 r4=*(const float4*)(row+nn);
      ym += r4.x*wv[nn] + r4.y*wv[nn+1] + r4.z*wv[nn+2] + r4.w*wv[nn+3];
    }
    q += ym*wv[m];
    sbp += wv[m]*yb[m];
  }
  float bias = eb[(g<<6)+c];
  float pz  = sbp + (qm==0 ? 16384.f*bias : 0.f);
  float pz2 = q + 2.f*bias*sbp + (qm==0 ? 16384.f*bias*bias : 0.f);
  red[t]=pz; red[256+t]=pz2;
  __syncthreads();
  for (int s=128;s>0;s>>=1){
    if (t<s){ red[t]+=red[t+s]; red[256+t]+=red[256+t+s]; }
    __syncthreads();
  }
  if (t==0){
    const float N=64.f*16384.f;
    float mu = red[0]/N;
    float var = red[256]/N - mu*mu;
    stats[bg*2]=mu; stats[bg*2+1]=rsqrtf(var+1e-5f);
  }
}

// ---- final MFMA: z = expand(y) (bf16 MFMA), GN apply + gelu + residual -> NCHW
__global__ __launch_bounds__(256) void k_final(const float* __restrict__ y,
    const ushort* __restrict__ ewb, const float* __restrict__ eb,
    const float* __restrict__ stats, const float* __restrict__ gamma,
    const float* __restrict__ beta, const float* __restrict__ feat,
    float* __restrict__ out){
  __shared__ ushort A[128*64];           // 16 KB bf16 y-tile
  __shared__ float T[64*132];            // 33 KB transpose buffer (pad 132)
  int t = threadIdx.x;
  int b = blockIdx.y, p0 = blockIdx.x*128;
  int lane = t & 63, w = t >> 6, ln = lane & 15, qd = lane >> 4;
  {
    int px = t>>1, ch0 = (t&1)*32;
    const float* yp = y + ((size_t)(b*HW + p0 + px))*64 + ch0;
    #pragma unroll
    for (int q=0;q<4;q++){
      float4 va = *(const float4*)(yp + q*8);
      float4 vb = *(const float4*)(yp + q*8 + 4);
      unsigned u0 = f2bf(va.x)|(f2bf(va.y)<<16);
      unsigned u1 = f2bf(va.z)|(f2bf(va.w)<<16);
      unsigned u2 = f2bf(vb.x)|(f2bf(vb.y)<<16);
      unsigned u3 = f2bf(vb.z)|(f2bf(vb.w)<<16);
      int chunk16 = (ch0 + q*8) >> 3;
      int phys = chunk16 ^ (px&7);
      *(uint4*)((char*)A + px*128 + phys*16) = make_uint4(u0,u1,u2,u3);
    }
  }
  __syncthreads();
  float mu = stats[((b<<2)+w)*2], rstd = stats[((b<<2)+w)*2+1];
  const float* fb = feat + (size_t)b*CC*HW + p0;
  float* ob = out + (size_t)b*CC*HW + p0;
  for (int nt=0;nt<4;nt++){
    int nch = (w<<6) + (nt<<4) + ln;
    const ushort* wb = ewb + (size_t)nch*64 + (qd<<3);
    bf16x8 b0 = *(const bf16x8*)wb;
    bf16x8 b1 = *(const bf16x8*)(wb + 32);
    f32x4 acc[8];
    #pragma unroll
    for (int pt=0;pt<8;pt++) acc[pt] = (f32x4){0.f,0.f,0.f,0.f};
    #pragma unroll
    for (int pt=0;pt<8;pt++){
      int m = (pt<<4) + ln;
      int ch0 = qd ^ (m&7), ch1 = (4+qd) ^ (m&7);
      bf16x8 a0 = *(bf16x8*)(A + (m<<6) + (ch0<<3));
      acc[pt] = __builtin_amdgcn_mfma_f32_16x16x32_bf16(a0, b0, acc[pt], 0,0,0);
      bf16x8 a1 = *(bf16x8*)(A + (m<<6) + (ch1<<3));
      acc[pt] = __builtin_amdgcn_mfma_f32_16x16x32_bf16(a1, b1, acc[pt], 0,0,0);
    }
    float bias = eb[nch];
    #pragma unroll
    for (int pt=0;pt<8;pt++){
      float4 v = make_float4(acc[pt][0]+bias, acc[pt][1]+bias,
                             acc[pt][2]+bias, acc[pt][3]+bias);
      *(float4*)&T[((w<<4)+ln)*132 + (pt<<4) + (qd<<2)] = v;
    }
    int orow = (w<<4) + (lane>>2);
    int c = (w<<6) + (nt<<4) + (lane>>2);
    float ga = gamma[c], be = beta[c];
    const float* frow = fb + (size_t)c*HW;
    float* orow_p = ob + (size_t)c*HW;
    #pragma unroll
    for (int it=0; it<8; it++){
      int px = it*16 + (lane&3)*4;
      float4 z = *(float4*)&T[orow*132 + px];
      float4 f = *(const float4*)(frow + px);
      float4 o;
      o.x = f.x + gelu_f((z.x-mu)*rstd*ga + be);
      o.y = f.y + gelu_f((z.y-mu)*rstd*ga + be);
      o.z = f.z + gelu_f((z.z-mu)*rstd*ga + be);
      o.w = f.w + gelu_f((z.w-mu)*rstd*ga + be);
      *(float4*)(orow_p + px) = o;
    }
  }
}

extern "C" void kernel_launch(void* const* d_in, const int* in_sizes, int n_in,
                              void* d_out, int out_size, void* d_ws, size_t ws_size,
                              hipStream_t stream){
  const float* feat = (const float*)d_in[0];
  const float* wind = (const float*)d_in[1];
  const float* cw   = (const float*)d_in[2];
  const float* cb   = (const float*)d_in[3];
  const float* w1   = (const float*)d_in[4];
  const float* b1   = (const float*)d_in[5];
  const float* w2   = (const float*)d_in[6];
  const float* b2   = (const float*)d_in[7];
  const float* dw   = (const float*)d_in[8];
  const float* db   = (const float*)d_in[9];
  const float* ew   = (const float*)d_in[10];
  const float* ebias= (const float*)d_in[11];
  const float* gg   = (const float*)d_in[12];
  const float* gb   = (const float*)d_in[13];
  float* ws = (float*)d_ws;
  float* x_nhwc   = ws;                    // 8388608
  float* y_nhwc   = ws + 8388608;          // 8388608
  float* h_nhwc   = ws + 16777216;         // 4194304 (reused as partY2 after off2)
  float* off_nhwc = ws + 20971520;         // 2359296 (reused as partYb after deform)
  ushort* bt      = (ushort*)(ws + 23330816); // 36864 ush = 18432 fl
  ushort* cwb     = (ushort*)(ws + 23349248); // 16384 ush = 8192 fl
  ushort* ewb     = (ushort*)(ws + 23357440); // 16384 ush = 8192 fl
  float* Y2       = ws + 23365632;         // 32768
  float* ybar     = ws + 23398400;         // 512
  float* stats    = ws + 23398912;         // 64
  float* partY2   = h_nhwc;                // 1024*4096 floats, dead after off2
  float* partYb   = off_nhwc;              // 1024*64 floats, dead after deform
  k_prep<<<272,256,0,stream>>>(dw, cw, ew, bt, cwb, ewb);
  k_compress<<<dim3(128,8),256,0,stream>>>(feat, cwb, cb, x_nhwc);
  k_off1<<<dim3(64,8),256,0,stream>>>(wind, w1, b1, h_nhwc);
  k_off2<<<dim3(64,8),256,0,stream>>>(h_nhwc, w2, b2, off_nhwc);
  k_deform<<<1024,256,0,stream>>>(x_nhwc, off_nhwc, bt, db, y_nhwc);
  k_stats<<<dim3(128,8),256,0,stream>>>(y_nhwc, partY2, partYb);
  k_reduce<<<dim3(5,8),256,0,stream>>>(partY2, partYb, Y2, ybar);
  k_gn<<<32,256,0,stream>>>(Y2, ybar, ew, ebias, stats);
  k_final<<<dim3(128,8),256,0,stream>>>(y_nhwc, ewb, ebias, stats, gg, gb, feat, (float*)d_out);
}

// Round 2
// 520.096 us; speedup vs baseline: 1.3878x; 1.0205x over previous
//
#include <hip/hip_runtime.h>
#include <math.h>

// WindAdvectionBlock: B=8, C=256, H=W=128, mid=64
// compress(1x1,MFMA) -> off1+gelu -> off2 -> deform(MFMA, coalesced gather,
// XCD-swizzled) -> [analytic GN stats, 2-stage non-atomic] -> final(MFMA
// expand+GN+gelu+residual, direct-from-acc epilogue)

#define BB 8
#define CC 256
#define HW 16384
#define MID 64

typedef __attribute__((ext_vector_type(8))) short bf16x8;
typedef __attribute__((ext_vector_type(4))) float f32x4;

__device__ __forceinline__ float gelu_f(float v){
  return 0.5f*v*(1.0f + erff(v*0.7071067811865476f));
}
__device__ __forceinline__ unsigned f2bf(float f){
  union { float f; unsigned u; } v; v.f = f;
  unsigned u = v.u;
  u += 0x7fff + ((u >> 16) & 1);   // RNE
  return (u >> 16);
}

// ---- prep: bt bf16 [9][64o][64c] from dw [64o][64c][9]; cwb bf16 [64o][256c];
//            ewb bf16 [256o][64c]
__global__ void k_prep(const float* __restrict__ dw, const float* __restrict__ cw,
                       const float* __restrict__ ew, ushort* __restrict__ bt,
                       ushort* __restrict__ cwb, ushort* __restrict__ ewb){
  int i = blockIdx.x*256 + threadIdx.x;
  if (i < 36864){
    int k = i >> 12, r = i & 4095;
    int o = r >> 6, c = r & 63;
    bt[i] = (ushort)f2bf(dw[(o*64+c)*9 + k]);
  }
  int j = i - 36864;
  if (j >= 0 && j < 16384) cwb[j] = (ushort)f2bf(cw[j]);
  int l = i - 53248;
  if (l >= 0 && l < 16384) ewb[l] = (ushort)f2bf(ew[l]);
}

// ---- compress 1x1 via MFMA: feat NCHW -> x NHWC [b][p][64]
// block = 128 px; K-loop 4 tiles of 64 ch; A staged via register transpose.
__global__ __launch_bounds__(256) void k_compress(const float* __restrict__ feat,
    const ushort* __restrict__ cwb, const float* __restrict__ cb, float* __restrict__ xo){
  __shared__ ushort A[128*64];           // 16 KB, [px][64c] bf16, 16B chunks xor px&7
  int t = threadIdx.x;
  int b = blockIdx.y, p0 = blockIdx.x*128;
  int lane = t & 63, w = t >> 6, ln = lane & 15, qd = lane >> 4;
  int n = (w<<4) + ln;                   // out channel
  int cg = t >> 4, pxg = t & 15;         // staging: 4-ch group, 8-px group
  f32x4 acc[8];
  #pragma unroll
  for (int pt=0;pt<8;pt++) acc[pt] = (f32x4){0.f,0.f,0.f,0.f};
  for (int kt=0;kt<4;kt++){
    // load 4 channels x 8 px into regs
    const float* fb = feat + ((size_t)(b*CC + kt*64 + cg*4))*HW + p0 + pxg*8;
    float v[4][8];
    #pragma unroll
    for (int i=0;i<4;i++){
      *(float4*)&v[i][0] = *(const float4*)(fb + (size_t)i*HW);
      *(float4*)&v[i][4] = *(const float4*)(fb + (size_t)i*HW + 4);
    }
    __syncthreads();                     // prev tile's readers done
    #pragma unroll
    for (int j=0;j<8;j++){
      int px = pxg*8 + j;
      unsigned lo = f2bf(v[0][j]) | (f2bf(v[1][j])<<16);
      unsigned hi = f2bf(v[2][j]) | (f2bf(v[3][j])<<16);
      int chunk = (cg>>1) ^ (px&7);
      *(uint2*)((char*)A + px*128 + chunk*16 + (cg&1)*8) = make_uint2(lo,hi);
    }
    __syncthreads();
    const ushort* wb = cwb + (size_t)n*256 + kt*64 + (qd<<3);
    bf16x8 b0 = *(const bf16x8*)wb;
    bf16x8 b1 = *(const bf16x8*)(wb + 32);
    #pragma unroll
    for (int pt=0;pt<8;pt++){
      int m = (pt<<4) + ln;
      int ch0 = qd ^ (m&7), ch1 = (4+qd) ^ (m&7);
      bf16x8 a0 = *(bf16x8*)(A + (m<<6) + (ch0<<3));
      acc[pt] = __builtin_amdgcn_mfma_f32_16x16x32_bf16(a0, b0, acc[pt], 0,0,0);
      bf16x8 a1 = *(bf16x8*)(A + (m<<6) + (ch1<<3));
      acc[pt] = __builtin_amdgcn_mfma_f32_16x16x32_bf16(a1, b1, acc[pt], 0,0,0);
    }
  }
  float bias = cb[n];
  float* xp = xo + ((size_t)(b*HW + p0))*64 + n;
  #pragma unroll
  for (int pt=0;pt<8;pt++){
    #pragma unroll
    for (int rg=0;rg<4;rg++){
      int px = (pt<<4) + (qd<<2) + rg;
      xp[(size_t)px*64] = acc[pt][rg] + bias;
    }
  }
}

// ---- off1: wind [b][2][H][W] -> h NHWC [b][p][32], conv3x3 pad1 + gelu
__global__ __launch_bounds__(256) void k_off1(const float* __restrict__ wind,
    const float* __restrict__ w1, const float* __restrict__ b1, float* __restrict__ ho){
  __shared__ float wl[576];
  int t=threadIdx.x;
  for (int i=t;i<576;i+=256) wl[i]=w1[i];
  __syncthreads();
  int b=blockIdx.y; int p=blockIdx.x*256+t;
  int y=p>>7, x=p&127;
  float tap[18];
  #pragma unroll
  for (int c=0;c<2;c++){
    #pragma unroll
    for (int ki=0;ki<3;ki++){
      #pragma unroll
      for (int kj=0;kj<3;kj++){
        int yy=y+ki-1, xx=x+kj-1;
        float v=0.f;
        if ((unsigned)yy<128u && (unsigned)xx<128u)
          v = wind[((size_t)b*2+c)*HW + (yy<<7)+xx];
        tap[c*9+ki*3+kj]=v;
      }
    }
  }
  float outv[32];
  #pragma unroll
  for (int o=0;o<32;o++){
    float a=b1[o];
    #pragma unroll
    for (int i=0;i<18;i++) a += tap[i]*wl[o*18+i];
    outv[o]=gelu_f(a);
  }
  float* hp = ho + ((size_t)(b*HW+p))*32;
  #pragma unroll
  for (int o=0;o<32;o+=4) *(float4*)(hp+o)=make_float4(outv[o],outv[o+1],outv[o+2],outv[o+3]);
}

// ---- off2: h NHWC [b][p][32] -> offsets NHWC [b][p][18], conv3x3 pad1
__global__ __launch_bounds__(256) void k_off2(const float* __restrict__ h,
    const float* __restrict__ w2, const float* __restrict__ b2, float* __restrict__ oo){
  __shared__ float wl[9*18*32];
  int t=threadIdx.x;
  for (int i=t;i<5184;i+=256){
    int k=i/576; int r=i-k*576; int o=r>>5; int c=r&31;
    wl[i] = w2[(o*32+c)*9+k];
  }
  __syncthreads();
  int b=blockIdx.y; int p=blockIdx.x*256+t;
  int y=p>>7, x=p&127;
  float acc[18];
  #pragma unroll
  for (int o=0;o<18;o++) acc[o]=b2[o];
  for (int ki=0;ki<3;ki++){
    for (int kj=0;kj<3;kj++){
      int k = ki*3+kj;
      int yy=y+ki-1, xx=x+kj-1;
      float4 hv[8];
      if ((unsigned)yy<128u && (unsigned)xx<128u){
        const float* hp = h + ((size_t)(b*HW) + (yy<<7)+xx)*32;
        #pragma unroll
        for (int q=0;q<8;q++) hv[q]=*(const float4*)(hp+q*4);
      } else {
        #pragma unroll
        for (int q=0;q<8;q++) hv[q]=make_float4(0.f,0.f,0.f,0.f);
      }
      const float* wk = &wl[k*576];
      #pragma unroll
      for (int o=0;o<18;o++){
        float a=acc[o];
        #pragma unroll
        for (int q=0;q<8;q++){
          float4 w4 = *(const float4*)(wk + o*32 + q*4);
          a += hv[q].x*w4.x + hv[q].y*w4.y + hv[q].z*w4.z + hv[q].w*w4.w;
        }
        acc[o]=a;
      }
    }
  }
  float* op = oo + ((size_t)(b*HW+p))*18;
  #pragma unroll
  for (int o=0;o<18;o+=2) *(float2*)(op+o)=make_float2(acc[o],acc[o+1]);
}

// ---- deform conv MFMA, coalesced gather.
// Grid 1024 linear: b = blk&7 (XCD locality), r = blk>>3.
__global__ __launch_bounds__(256) void k_deform(
    const float* __restrict__ x, const float* __restrict__ off,
    const ushort* __restrict__ bt, const float* __restrict__ db,
    float* __restrict__ yo){
  __shared__ ushort A[128*64];           // 16 KB
  __shared__ float offs[128*18];         // 9 KB
  int t = threadIdx.x;
  int blk = blockIdx.x;
  int b = blk & 7, r = blk >> 3;
  int p0 = r*128;
  const float* offg = off + ((size_t)(b*HW + p0))*18;
  for (int i=t;i<576;i+=256)
    *(float4*)(offs + i*4) = *(const float4*)(offg + i*4);
  __syncthreads();
  int lane = t & 63, w = t >> 6, ln = lane & 15, qd = lane >> 4;
  int n = (w<<4) + ln;
  const float* xb = x + (size_t)b*HW*64;
  f32x4 acc[8];
  #pragma unroll
  for (int pt=0;pt<8;pt++) acc[pt] = (f32x4){0.f,0.f,0.f,0.f};

  for (int k=0;k<9;k++){
    int ki = k/3, kj = k - ki*3;
    const ushort* btk = bt + (size_t)(((k<<6) + n)<<6) + (qd<<3);
    bf16x8 bf0 = *(const bf16x8*)btk;
    bf16x8 bf1 = *(const bf16x8*)(btk + 32);
    __syncthreads();                     // prev tap's MFMA reads done
    #pragma unroll
    for (int pp=0;pp<8;pp++){
      int p = (w<<5) + (pp<<2) + qd;     // pixel (x-coord) 0..127
      float2 dd = *(const float2*)(offs + p*18 + 2*k);
      float py  = dd.x + (float)(r + ki - 1);
      float pxs = dd.y + (float)(p + kj - 1);
      float y0f = floorf(py), x0f = floorf(pxs);
      float fy = py - y0f, fx = pxs - x0f;
      int y0 = (int)y0f, x0 = (int)x0f;
      float w00=(1.f-fy)*(1.f-fx), w01=(1.f-fy)*fx, w10=fy*(1.f-fx), w11=fy*fx;
      bool v0=((unsigned)y0<128u), v1=((unsigned)(y0+1)<128u);
      bool u0=((unsigned)x0<128u), u1=((unsigned)(x0+1)<128u);
      w00 = (v0&&u0)? w00 : 0.f;  w01 = (v0&&u1)? w01 : 0.f;
      w10 = (v1&&u0)? w10 : 0.f;  w11 = (v1&&u1)? w11 : 0.f;
      int y0c = min(max(y0,0),127), y1c = min(max(y0+1,0),127);
      int x0c = min(max(x0,0),127), x1c = min(max(x0+1,0),127);
      int cofs = (ln<<2);
      const float4* r00 = (const float4*)(xb + (size_t)y0c*8192 + x0c*64 + cofs);
      const float4* r01 = (const float4*)(xb + (size_t)y0c*8192 + x1c*64 + cofs);
      const float4* r10 = (const float4*)(xb + (size_t)y1c*8192 + x0c*64 + cofs);
      const float4* r11 = (const float4*)(xb + (size_t)y1c*8192 + x1c*64 + cofs);
      float4 a00=*r00, a01=*r01, a10=*r10, a11=*r11;
      float4 s;
      s.x = a00.x*w00 + a01.x*w01 + a10.x*w10 + a11.x*w11;
      s.y = a00.y*w00 + a01.y*w01 + a10.y*w10 + a11.y*w11;
      s.z = a00.z*w00 + a01.z*w01 + a10.z*w10 + a11.z*w11;
      s.w = a00.w*w00 + a01.w*w01 + a10.w*w10 + a11.w*w11;
      unsigned lo = f2bf(s.x) | (f2bf(s.y)<<16);
      unsigned hi = f2bf(s.z) | (f2bf(s.w)<<16);
      int chunk = (ln>>1) ^ (p&7);
      *(uint2*)((char*)A + p*128 + chunk*16 + (ln&1)*8) = make_uint2(lo,hi);
    }
    __syncthreads();                     // A tile ready
    #pragma unroll
    for (int pt=0;pt<8;pt++){
      int m = (pt<<4) + ln;
      int ch0 = qd ^ (m&7), ch1 = (4+qd) ^ (m&7);
      bf16x8 a0 = *(bf16x8*)(A + (m<<6) + (ch0<<3));
      acc[pt] = __builtin_amdgcn_mfma_f32_16x16x32_bf16(a0, bf0, acc[pt], 0,0,0);
      bf16x8 a1 = *(bf16x8*)(A + (m<<6) + (ch1<<3));
      acc[pt] = __builtin_amdgcn_mfma_f32_16x16x32_bf16(a1, bf1, acc[pt], 0,0,0);
    }
  }
  float bias = db[n];
  float* yp = yo + ((size_t)(b*HW + p0))*64 + n;
  #pragma unroll
  for (int pt=0;pt<8;pt++){
    #pragma unroll
    for (int rg=0;rg<4;rg++){
      int px = (pt<<4) + (qd<<2) + rg;
      yp[(size_t)px*64] = acc[pt][rg] + bias;
    }
  }
}

// ---- stats stage A: per-block partial Y2 (64x64) + ybar (64), NO atomics.
// Thread t owns a 4x4 output tile: ib = t&15 (rows), jb = t>>4 (cols).
__global__ __launch_bounds__(256) void k_stats(const float* __restrict__ y,
    float* __restrict__ partY2, float* __restrict__ partYb){
  __shared__ float yt[128*64];
  int t=threadIdx.x; int b=blockIdx.y; int r=blockIdx.x;
  const float* yp = y + ((size_t)(b*HW) + (size_t)r*128)*64;
  for (int i=t*4;i<8192;i+=1024) *(float4*)&yt[i]=*(const float4*)(yp+i);
  __syncthreads();
  int ib = t & 15, jb = t >> 4;
  float acc[4][4];
  #pragma unroll
  for (int a=0;a<4;a++)
    #pragma unroll
    for (int c=0;c<4;c++) acc[a][c]=0.f;
  for (int p=0;p<128;p++){
    float4 vi = *(const float4*)&yt[(p<<6)+(ib<<2)];
    float4 vj = *(const float4*)&yt[(p<<6)+(jb<<2)];
    float fi[4]={vi.x,vi.y,vi.z,vi.w};
    float fj[4]={vj.x,vj.y,vj.z,vj.w};
    #pragma unroll
    for (int a=0;a<4;a++)
      #pragma unroll
      for (int c=0;c<4;c++) acc[a][c] += fi[a]*fj[c];
  }
  float* pb = partY2 + ((size_t)(b*128+r))*4096;
  #pragma unroll
  for (int a=0;a<4;a++)
    *(float4*)(pb + (ib*4+a)*64 + jb*4) =
        make_float4(acc[a][0],acc[a][1],acc[a][2],acc[a][3]);
  if (t < 64){
    float s=0.f;
    for (int p=0;p<128;p++) s += yt[(p<<6)+t];
    partYb[(size_t)(b*128+r)*64 + t] = s;
  }
}

// ---- stats stage B: fold 128 partials per batch into Y2 / ybar (coalesced).
__global__ __launch_bounds__(256) void k_reduce(const float* __restrict__ partY2,
    const float* __restrict__ partYb, float* __restrict__ Y2,
    float* __restrict__ ybar){
  int t=threadIdx.x; int b=blockIdx.y;
  if (blockIdx.x < 4){
    int e = (blockIdx.x*256 + t)*4;
    const float* p = partY2 + ((size_t)b*128)*4096 + e;
    float4 s=make_float4(0.f,0.f,0.f,0.f);
    for (int r=0;r<128;r++){
      float4 v=*(const float4*)(p+(size_t)r*4096);
      s.x+=v.x; s.y+=v.y; s.z+=v.z; s.w+=v.w;
    }
    *(float4*)(Y2+((size_t)b<<12)+e)=s;
  } else if (t < 16){
    int e = t*4;
    const float* p = partYb + (size_t)b*8192 + e;
    float4 s=make_float4(0.f,0.f,0.f,0.f);
    for (int r=0;r<128;r++){
      float4 v=*(const float4*)(p+r*64);
      s.x+=v.x; s.y+=v.y; s.z+=v.z; s.w+=v.w;
    }
    *(float4*)(ybar+(b<<6)+e)=s;
  }
}

// ---- analytic GN stats per (b,g): mu, rstd of z = expand(y)
__global__ __launch_bounds__(256) void k_gn(const float* __restrict__ Y2,
    const float* __restrict__ ybar, const float* __restrict__ ew,
    const float* __restrict__ eb, float* __restrict__ stats){
  __shared__ float wsm[64*65];
  __shared__ float red[512];
  int t=threadIdx.x;
  int bg=blockIdx.x, b=bg>>2, g=bg&3;
  for (int i=t;i<4096;i+=256){
    int c=i>>6, m=i&63;
    wsm[c*65+m] = ew[(((size_t)g<<6)+c)*64 + m];
  }
  __syncthreads();
  int c = t&63, qm = t>>6;
  const float* wv = &wsm[c*65];
  const float* Y2b = Y2 + ((size_t)b<<12);
  const float* yb = ybar + (b<<6);
  float q=0.f, sbp=0.f;
  for (int m=qm*16; m<qm*16+16; m++){
    const float* row = Y2b + (m<<6);
    float ym=0.f;
    for (int nn=0;nn<64;nn+=4){
      float4 r4=*(const float4*)(row+nn);
      ym += r4.x*wv[nn] + r4.y*wv[nn+1] + r4.z*wv[nn+2] + r4.w*wv[nn+3];
    }
    q += ym*wv[m];
    sbp += wv[m]*yb[m];
  }
  float bias = eb[(g<<6)+c];
  float pz  = sbp + (qm==0 ? 16384.f*bias : 0.f);
  float pz2 = q + 2.f*bias*sbp + (qm==0 ? 16384.f*bias*bias : 0.f);
  red[t]=pz; red[256+t]=pz2;
  __syncthreads();
  for (int s=128;s>0;s>>=1){
    if (t<s){ red[t]+=red[t+s]; red[256+t]+=red[256+t+s]; }
    __syncthreads();
  }
  if (t==0){
    const float N=64.f*16384.f;
    float mu = red[0]/N;
    float var = red[256]/N - mu*mu;
    stats[bg*2]=mu; stats[bg*2+1]=rsqrtf(var+1e-5f);
  }
}

// ---- final MFMA: z = expand(y) (bf16 MFMA), GN apply + gelu + residual -> NCHW
// Direct-from-acc epilogue: no T buffer, LDS = 16 KB (A only).
// acc[pt][rg] = z for (channel nch=(w<<6)+(nt<<4)+ln, px=pt*16+qd*4+rg).
// Store float4 per (pt): lanes qd=0..3 of each ln cover 64B contiguous px.
__global__ __launch_bounds__(256) void k_final(const float* __restrict__ y,
    const ushort* __restrict__ ewb, const float* __restrict__ eb,
    const float* __restrict__ stats, const float* __restrict__ gamma,
    const float* __restrict__ beta, const float* __restrict__ feat,
    float* __restrict__ out){
  __shared__ ushort A[128*64];           // 16 KB bf16 y-tile
  int t = threadIdx.x;
  int b = blockIdx.y, p0 = blockIdx.x*128;
  int lane = t & 63, w = t >> 6, ln = lane & 15, qd = lane >> 4;
  {
    int px = t>>1, ch0 = (t&1)*32;
    const float* yp = y + ((size_t)(b*HW + p0 + px))*64 + ch0;
    #pragma unroll
    for (int q=0;q<4;q++){
      float4 va = *(const float4*)(yp + q*8);
      float4 vb = *(const float4*)(yp + q*8 + 4);
      unsigned u0 = f2bf(va.x)|(f2bf(va.y)<<16);
      unsigned u1 = f2bf(va.z)|(f2bf(va.w)<<16);
      unsigned u2 = f2bf(vb.x)|(f2bf(vb.y)<<16);
      unsigned u3 = f2bf(vb.z)|(f2bf(vb.w)<<16);
      int chunk16 = (ch0 + q*8) >> 3;
      int phys = chunk16 ^ (px&7);
      *(uint4*)((char*)A + px*128 + phys*16) = make_uint4(u0,u1,u2,u3);
    }
  }
  __syncthreads();
  float mu = stats[((b<<2)+w)*2], rstd = stats[((b<<2)+w)*2+1];
  const float* fb = feat + (size_t)b*CC*HW + p0;
  float* ob = out + (size_t)b*CC*HW + p0;
  for (int nt=0;nt<4;nt++){
    int nch = (w<<6) + (nt<<4) + ln;
    const ushort* wb = ewb + (size_t)nch*64 + (qd<<3);
    bf16x8 b0 = *(const bf16x8*)wb;
    bf16x8 b1 = *(const bf16x8*)(wb + 32);
    f32x4 acc[8];
    #pragma unroll
    for (int pt=0;pt<8;pt++) acc[pt] = (f32x4){0.f,0.f,0.f,0.f};
    #pragma unroll
    for (int pt=0;pt<8;pt++){
      int m = (pt<<4) + ln;
      int ch0 = qd ^ (m&7), ch1 = (4+qd) ^ (m&7);
      bf16x8 a0 = *(bf16x8*)(A + (m<<6) + (ch0<<3));
      acc[pt] = __builtin_amdgcn_mfma_f32_16x16x32_bf16(a0, b0, acc[pt], 0,0,0);
      bf16x8 a1 = *(bf16x8*)(A + (m<<6) + (ch1<<3));
      acc[pt] = __builtin_amdgcn_mfma_f32_16x16x32_bf16(a1, b1, acc[pt], 0,0,0);
    }
    float bias = eb[nch];
    float ga = gamma[nch], be = beta[nch];
    float gr = rstd*ga;
    float ofs = (bias - mu)*gr + be;     // z*gr + ofs == (z+bias-mu)*rstd*ga + be
    const float* frow = fb + (size_t)nch*HW;
    float* orow = ob + (size_t)nch*HW;
    #pragma unroll
    for (int pt=0;pt<8;pt++){
      int px = (pt<<4) + (qd<<2);
      float4 f = *(const float4*)(frow + px);
      float4 o;
      o.x = f.x + gelu_f(acc[pt][0]*gr + ofs);
      o.y = f.y + gelu_f(acc[pt][1]*gr + ofs);
      o.z = f.z + gelu_f(acc[pt][2]*gr + ofs);
      o.w = f.w + gelu_f(acc[pt][3]*gr + ofs);
      *(float4*)(orow + px) = o;
    }
  }
}

extern "C" void kernel_launch(void* const* d_in, const int* in_sizes, int n_in,
                              void* d_out, int out_size, void* d_ws, size_t ws_size,
                              hipStream_t stream){
  const float* feat = (const float*)d_in[0];
  const float* wind = (const float*)d_in[1];
  const float* cw   = (const float*)d_in[2];
  const float* cb   = (const float*)d_in[3];
  const float* w1   = (const float*)d_in[4];
  const float* b1   = (const float*)d_in[5];
  const float* w2   = (const float*)d_in[6];
  const float* b2   = (const float*)d_in[7];
  const float* dw   = (const float*)d_in[8];
  const float* db   = (const float*)d_in[9];
  const float* ew   = (const float*)d_in[10];
  const float* ebias= (const float*)d_in[11];
  const float* gg   = (const float*)d_in[12];
  const float* gb   = (const float*)d_in[13];
  float* ws = (float*)d_ws;
  float* x_nhwc   = ws;                    // 8388608
  float* y_nhwc   = ws + 8388608;          // 8388608
  float* h_nhwc   = ws + 16777216;         // 4194304 (reused as partY2 after off2)
  float* off_nhwc = ws + 20971520;         // 2359296 (reused as partYb after deform)
  ushort* bt      = (ushort*)(ws + 23330816); // 36864 ush = 18432 fl
  ushort* cwb     = (ushort*)(ws + 23349248); // 16384 ush = 8192 fl
  ushort* ewb     = (ushort*)(ws + 23357440); // 16384 ush = 8192 fl
  float* Y2       = ws + 23365632;         // 32768
  float* ybar     = ws + 23398400;         // 512
  float* stats    = ws + 23398912;         // 64
  float* partY2   = h_nhwc;                // 1024*4096 floats, dead after off2
  float* partYb   = off_nhwc;              // 1024*64 floats, dead after deform
  k_prep<<<272,256,0,stream>>>(dw, cw, ew, bt, cwb, ewb);
  k_compress<<<dim3(128,8),256,0,stream>>>(feat, cwb, cb, x_nhwc);
  k_off1<<<dim3(64,8),256,0,stream>>>(wind, w1, b1, h_nhwc);
  k_off2<<<dim3(64,8),256,0,stream>>>(h_nhwc, w2, b2, off_nhwc);
  k_deform<<<1024,256,0,stream>>>(x_nhwc, off_nhwc, bt, db, y_nhwc);
  k_stats<<<dim3(128,8),256,0,stream>>>(y_nhwc, partY2, partYb);
  k_reduce<<<dim3(5,8),256,0,stream>>>(partY2, partYb, Y2, ybar);
  k_gn<<<32,256,0,stream>>>(Y2, ybar, ew, ebias, stats);
  k_final<<<dim3(128,8),256,0,stream>>>(y_nhwc, ewb, ebias, stats, gg, gb, feat, (float*)d_out);
}

// Round 3
// 509.116 us; speedup vs baseline: 1.4178x; 1.0216x over previous
//
#include <hip/hip_runtime.h>
#include <math.h>

// WindAdvectionBlock: B=8, C=256, H=W=128, mid=64
// compress(1x1,MFMA) -> off1+gelu -> off2 -> deform(MFMA, coalesced gather,
// XCD-swizzled, bf16 y out) -> [analytic GN stats, 2-stage non-atomic] ->
// final(MFMA expand+GN+gelu+residual, 64-px tiles, direct-from-acc epilogue)

#define BB 8
#define CC 256
#define HW 16384
#define MID 64

typedef __attribute__((ext_vector_type(8))) short bf16x8;
typedef __attribute__((ext_vector_type(4))) float f32x4;

__device__ __forceinline__ float gelu_f(float v){
  return 0.5f*v*(1.0f + erff(v*0.7071067811865476f));
}
__device__ __forceinline__ unsigned f2bf(float f){
  union { float f; unsigned u; } v; v.f = f;
  unsigned u = v.u;
  u += 0x7fff + ((u >> 16) & 1);   // RNE
  return (u >> 16);
}
__device__ __forceinline__ float bf2f(unsigned u){
  union { unsigned u; float f; } v; v.u = u; return v.f;
}

// ---- prep: bt bf16 [9][64o][64c] from dw [64o][64c][9]; cwb bf16 [64o][256c];
//            ewb bf16 [256o][64c]
__global__ void k_prep(const float* __restrict__ dw, const float* __restrict__ cw,
                       const float* __restrict__ ew, ushort* __restrict__ bt,
                       ushort* __restrict__ cwb, ushort* __restrict__ ewb){
  int i = blockIdx.x*256 + threadIdx.x;
  if (i < 36864){
    int k = i >> 12, r = i & 4095;
    int o = r >> 6, c = r & 63;
    bt[i] = (ushort)f2bf(dw[(o*64+c)*9 + k]);
  }
  int j = i - 36864;
  if (j >= 0 && j < 16384) cwb[j] = (ushort)f2bf(cw[j]);
  int l = i - 53248;
  if (l >= 0 && l < 16384) ewb[l] = (ushort)f2bf(ew[l]);
}

// ---- compress 1x1 via MFMA: feat NCHW -> x NHWC [b][p][64]
__global__ __launch_bounds__(256) void k_compress(const float* __restrict__ feat,
    const ushort* __restrict__ cwb, const float* __restrict__ cb, float* __restrict__ xo){
  __shared__ ushort A[128*64];           // 16 KB, [px][64c] bf16, 16B chunks xor px&7
  int t = threadIdx.x;
  int b = blockIdx.y, p0 = blockIdx.x*128;
  int lane = t & 63, w = t >> 6, ln = lane & 15, qd = lane >> 4;
  int n = (w<<4) + ln;                   // out channel
  int cg = t >> 4, pxg = t & 15;         // staging: 4-ch group, 8-px group
  f32x4 acc[8];
  #pragma unroll
  for (int pt=0;pt<8;pt++) acc[pt] = (f32x4){0.f,0.f,0.f,0.f};
  for (int kt=0;kt<4;kt++){
    const float* fb = feat + ((size_t)(b*CC + kt*64 + cg*4))*HW + p0 + pxg*8;
    float v[4][8];
    #pragma unroll
    for (int i=0;i<4;i++){
      *(float4*)&v[i][0] = *(const float4*)(fb + (size_t)i*HW);
      *(float4*)&v[i][4] = *(const float4*)(fb + (size_t)i*HW + 4);
    }
    __syncthreads();                     // prev tile's readers done
    #pragma unroll
    for (int j=0;j<8;j++){
      int px = pxg*8 + j;
      unsigned lo = f2bf(v[0][j]) | (f2bf(v[1][j])<<16);
      unsigned hi = f2bf(v[2][j]) | (f2bf(v[3][j])<<16);
      int chunk = (cg>>1) ^ (px&7);
      *(uint2*)((char*)A + px*128 + chunk*16 + (cg&1)*8) = make_uint2(lo,hi);
    }
    __syncthreads();
    const ushort* wb = cwb + (size_t)n*256 + kt*64 + (qd<<3);
    bf16x8 b0 = *(const bf16x8*)wb;
    bf16x8 b1 = *(const bf16x8*)(wb + 32);
    #pragma unroll
    for (int pt=0;pt<8;pt++){
      int m = (pt<<4) + ln;
      int ch0 = qd ^ (m&7), ch1 = (4+qd) ^ (m&7);
      bf16x8 a0 = *(bf16x8*)(A + (m<<6) + (ch0<<3));
      acc[pt] = __builtin_amdgcn_mfma_f32_16x16x32_bf16(a0, b0, acc[pt], 0,0,0);
      bf16x8 a1 = *(bf16x8*)(A + (m<<6) + (ch1<<3));
      acc[pt] = __builtin_amdgcn_mfma_f32_16x16x32_bf16(a1, b1, acc[pt], 0,0,0);
    }
  }
  float bias = cb[n];
  float* xp = xo + ((size_t)(b*HW + p0))*64 + n;
  #pragma unroll
  for (int pt=0;pt<8;pt++){
    #pragma unroll
    for (int rg=0;rg<4;rg++){
      int px = (pt<<4) + (qd<<2) + rg;
      xp[(size_t)px*64] = acc[pt][rg] + bias;
    }
  }
}

// ---- off1: wind [b][2][H][W] -> h NHWC [b][p][32], conv3x3 pad1 + gelu
__global__ __launch_bounds__(256) void k_off1(const float* __restrict__ wind,
    const float* __restrict__ w1, const float* __restrict__ b1, float* __restrict__ ho){
  __shared__ float wl[576];
  int t=threadIdx.x;
  for (int i=t;i<576;i+=256) wl[i]=w1[i];
  __syncthreads();
  int b=blockIdx.y; int p=blockIdx.x*256+t;
  int y=p>>7, x=p&127;
  float tap[18];
  #pragma unroll
  for (int c=0;c<2;c++){
    #pragma unroll
    for (int ki=0;ki<3;ki++){
      #pragma unroll
      for (int kj=0;kj<3;kj++){
        int yy=y+ki-1, xx=x+kj-1;
        float v=0.f;
        if ((unsigned)yy<128u && (unsigned)xx<128u)
          v = wind[((size_t)b*2+c)*HW + (yy<<7)+xx];
        tap[c*9+ki*3+kj]=v;
      }
    }
  }
  float outv[32];
  #pragma unroll
  for (int o=0;o<32;o++){
    float a=b1[o];
    #pragma unroll
    for (int i=0;i<18;i++) a += tap[i]*wl[o*18+i];
    outv[o]=gelu_f(a);
  }
  float* hp = ho + ((size_t)(b*HW+p))*32;
  #pragma unroll
  for (int o=0;o<32;o+=4) *(float4*)(hp+o)=make_float4(outv[o],outv[o+1],outv[o+2],outv[o+3]);
}

// ---- off2: h NHWC [b][p][32] -> offsets NHWC [b][p][18], conv3x3 pad1
__global__ __launch_bounds__(256) void k_off2(const float* __restrict__ h,
    const float* __restrict__ w2, const float* __restrict__ b2, float* __restrict__ oo){
  __shared__ float wl[9*18*32];
  int t=threadIdx.x;
  for (int i=t;i<5184;i+=256){
    int k=i/576; int r=i-k*576; int o=r>>5; int c=r&31;
    wl[i] = w2[(o*32+c)*9+k];
  }
  __syncthreads();
  int b=blockIdx.y; int p=blockIdx.x*256+t;
  int y=p>>7, x=p&127;
  float acc[18];
  #pragma unroll
  for (int o=0;o<18;o++) acc[o]=b2[o];
  for (int ki=0;ki<3;ki++){
    for (int kj=0;kj<3;kj++){
      int k = ki*3+kj;
      int yy=y+ki-1, xx=x+kj-1;
      float4 hv[8];
      if ((unsigned)yy<128u && (unsigned)xx<128u){
        const float* hp = h + ((size_t)(b*HW) + (yy<<7)+xx)*32;
        #pragma unroll
        for (int q=0;q<8;q++) hv[q]=*(const float4*)(hp+q*4);
      } else {
        #pragma unroll
        for (int q=0;q<8;q++) hv[q]=make_float4(0.f,0.f,0.f,0.f);
      }
      const float* wk = &wl[k*576];
      #pragma unroll
      for (int o=0;o<18;o++){
        float a=acc[o];
        #pragma unroll
        for (int q=0;q<8;q++){
          float4 w4 = *(const float4*)(wk + o*32 + q*4);
          a += hv[q].x*w4.x + hv[q].y*w4.y + hv[q].z*w4.z + hv[q].w*w4.w;
        }
        acc[o]=a;
      }
    }
  }
  float* op = oo + ((size_t)(b*HW+p))*18;
  #pragma unroll
  for (int o=0;o<18;o+=2) *(float2*)(op+o)=make_float2(acc[o],acc[o+1]);
}

// ---- deform conv MFMA, coalesced gather; y written as bf16 NHWC via LDS repack.
// Grid 1024 linear: b = blk&7 (XCD locality), r = blk>>3.
__global__ __launch_bounds__(256) void k_deform(
    const float* __restrict__ x, const float* __restrict__ off,
    const ushort* __restrict__ bt, const float* __restrict__ db,
    ushort* __restrict__ yo){
  __shared__ ushort A[128*64];           // 16 KB
  __shared__ float offs[128*18];         // 9 KB
  int t = threadIdx.x;
  int blk = blockIdx.x;
  int b = blk & 7, r = blk >> 3;
  int p0 = r*128;
  const float* offg = off + ((size_t)(b*HW + p0))*18;
  for (int i=t;i<576;i+=256)
    *(float4*)(offs + i*4) = *(const float4*)(offg + i*4);
  __syncthreads();
  int lane = t & 63, w = t >> 6, ln = lane & 15, qd = lane >> 4;
  int n = (w<<4) + ln;
  const float* xb = x + (size_t)b*HW*64;
  f32x4 acc[8];
  #pragma unroll
  for (int pt=0;pt<8;pt++) acc[pt] = (f32x4){0.f,0.f,0.f,0.f};

  for (int k=0;k<9;k++){
    int ki = k/3, kj = k - ki*3;
    const ushort* btk = bt + (size_t)(((k<<6) + n)<<6) + (qd<<3);
    bf16x8 bf0 = *(const bf16x8*)btk;
    bf16x8 bf1 = *(const bf16x8*)(btk + 32);
    __syncthreads();                     // prev tap's MFMA reads done
    #pragma unroll
    for (int pp=0;pp<8;pp++){
      int p = (w<<5) + (pp<<2) + qd;     // pixel (x-coord) 0..127
      float2 dd = *(const float2*)(offs + p*18 + 2*k);
      float py  = dd.x + (float)(r + ki - 1);
      float pxs = dd.y + (float)(p + kj - 1);
      float y0f = floorf(py), x0f = floorf(pxs);
      float fy = py - y0f, fx = pxs - x0f;
      int y0 = (int)y0f, x0 = (int)x0f;
      float w00=(1.f-fy)*(1.f-fx), w01=(1.f-fy)*fx, w10=fy*(1.f-fx), w11=fy*fx;
      bool v0=((unsigned)y0<128u), v1=((unsigned)(y0+1)<128u);
      bool u0=((unsigned)x0<128u), u1=((unsigned)(x0+1)<128u);
      w00 = (v0&&u0)? w00 : 0.f;  w01 = (v0&&u1)? w01 : 0.f;
      w10 = (v1&&u0)? w10 : 0.f;  w11 = (v1&&u1)? w11 : 0.f;
      int y0c = min(max(y0,0),127), y1c = min(max(y0+1,0),127);
      int x0c = min(max(x0,0),127), x1c = min(max(x0+1,0),127);
      int cofs = (ln<<2);
      const float4* r00 = (const float4*)(xb + (size_t)y0c*8192 + x0c*64 + cofs);
      const float4* r01 = (const float4*)(xb + (size_t)y0c*8192 + x1c*64 + cofs);
      const float4* r10 = (const float4*)(xb + (size_t)y1c*8192 + x0c*64 + cofs);
      const float4* r11 = (const float4*)(xb + (size_t)y1c*8192 + x1c*64 + cofs);
      float4 a00=*r00, a01=*r01, a10=*r10, a11=*r11;
      float4 s;
      s.x = a00.x*w00 + a01.x*w01 + a10.x*w10 + a11.x*w11;
      s.y = a00.y*w00 + a01.y*w01 + a10.y*w10 + a11.y*w11;
      s.z = a00.z*w00 + a01.z*w01 + a10.z*w10 + a11.z*w11;
      s.w = a00.w*w00 + a01.w*w01 + a10.w*w10 + a11.w*w11;
      unsigned lo = f2bf(s.x) | (f2bf(s.y)<<16);
      unsigned hi = f2bf(s.z) | (f2bf(s.w)<<16);
      int chunk = (ln>>1) ^ (p&7);
      *(uint2*)((char*)A + p*128 + chunk*16 + (ln&1)*8) = make_uint2(lo,hi);
    }
    __syncthreads();                     // A tile ready
    #pragma unroll
    for (int pt=0;pt<8;pt++){
      int m = (pt<<4) + ln;
      int ch0 = qd ^ (m&7), ch1 = (4+qd) ^ (m&7);
      bf16x8 a0 = *(bf16x8*)(A + (m<<6) + (ch0<<3));
      acc[pt] = __builtin_amdgcn_mfma_f32_16x16x32_bf16(a0, bf0, acc[pt], 0,0,0);
      bf16x8 a1 = *(bf16x8*)(A + (m<<6) + (ch1<<3));
      acc[pt] = __builtin_amdgcn_mfma_f32_16x16x32_bf16(a1, bf1, acc[pt], 0,0,0);
    }
  }
  __syncthreads();                       // all MFMA reads of A done
  float bias = db[n];
  // repack y tile as bf16 into A[px*64 + n] (linear [px][64ch] layout)
  #pragma unroll
  for (int pt=0;pt<8;pt++){
    #pragma unroll
    for (int rg=0;rg<4;rg++){
      int px = (pt<<4) + (qd<<2) + rg;
      A[(px<<6) + n] = (ushort)f2bf(acc[pt][rg] + bias);
    }
  }
  __syncthreads();
  // coalesced 16B stores: 1024 uint4 total, 4 per thread
  uint4* yq = (uint4*)(yo + ((size_t)(b*HW + p0))*64);
  const uint4* As = (const uint4*)A;
  #pragma unroll
  for (int q=0;q<4;q++) yq[t + q*256] = As[t + q*256];
}

// ---- stats stage A: per-block partial Y2 (64x64) + ybar (64), NO atomics.
// Reads bf16 y; stages f32 in LDS; thread t owns a 4x4 output tile.
__global__ __launch_bounds__(256) void k_stats(const ushort* __restrict__ y,
    float* __restrict__ partY2, float* __restrict__ partYb){
  __shared__ float yt[128*64];
  int t=threadIdx.x; int b=blockIdx.y; int r=blockIdx.x;
  const ushort* yp = y + ((size_t)(b*HW) + (size_t)r*128)*64;
  for (int i=t*8;i<8192;i+=2048){
    uint4 v = *(const uint4*)(yp+i);
    float4 f0, f1;
    f0.x = bf2f(v.x<<16); f0.y = bf2f(v.x&0xffff0000u);
    f0.z = bf2f(v.y<<16); f0.w = bf2f(v.y&0xffff0000u);
    f1.x = bf2f(v.z<<16); f1.y = bf2f(v.z&0xffff0000u);
    f1.z = bf2f(v.w<<16); f1.w = bf2f(v.w&0xffff0000u);
    *(float4*)&yt[i] = f0;
    *(float4*)&yt[i+4] = f1;
  }
  __syncthreads();
  int ib = t & 15, jb = t >> 4;
  float acc[4][4];
  #pragma unroll
  for (int a=0;a<4;a++)
    #pragma unroll
    for (int c=0;c<4;c++) acc[a][c]=0.f;
  for (int p=0;p<128;p++){
    float4 vi = *(const float4*)&yt[(p<<6)+(ib<<2)];
    float4 vj = *(const float4*)&yt[(p<<6)+(jb<<2)];
    float fi[4]={vi.x,vi.y,vi.z,vi.w};
    float fj[4]={vj.x,vj.y,vj.z,vj.w};
    #pragma unroll
    for (int a=0;a<4;a++)
      #pragma unroll
      for (int c=0;c<4;c++) acc[a][c] += fi[a]*fj[c];
  }
  float* pb = partY2 + ((size_t)(b*128+r))*4096;
  #pragma unroll
  for (int a=0;a<4;a++)
    *(float4*)(pb + (ib*4+a)*64 + jb*4) =
        make_float4(acc[a][0],acc[a][1],acc[a][2],acc[a][3]);
  if (t < 64){
    float s=0.f;
    for (int p=0;p<128;p++) s += yt[(p<<6)+t];
    partYb[(size_t)(b*128+r)*64 + t] = s;
  }
}

// ---- stats stage B: fold 128 partials per batch into Y2 / ybar (coalesced).
__global__ __launch_bounds__(256) void k_reduce(const float* __restrict__ partY2,
    const float* __restrict__ partYb, float* __restrict__ Y2,
    float* __restrict__ ybar){
  int t=threadIdx.x; int b=blockIdx.y;
  if (blockIdx.x < 4){
    int e = (blockIdx.x*256 + t)*4;
    const float* p = partY2 + ((size_t)b*128)*4096 + e;
    float4 s=make_float4(0.f,0.f,0.f,0.f);
    for (int r=0;r<128;r++){
      float4 v=*(const float4*)(p+(size_t)r*4096);
      s.x+=v.x; s.y+=v.y; s.z+=v.z; s.w+=v.w;
    }
    *(float4*)(Y2+((size_t)b<<12)+e)=s;
  } else if (t < 16){
    int e = t*4;
    const float* p = partYb + (size_t)b*8192 + e;
    float4 s=make_float4(0.f,0.f,0.f,0.f);
    for (int r=0;r<128;r++){
      float4 v=*(const float4*)(p+r*64);
      s.x+=v.x; s.y+=v.y; s.z+=v.z; s.w+=v.w;
    }
    *(float4*)(ybar+(b<<6)+e)=s;
  }
}

// ---- analytic GN stats per (b,g): mu, rstd of z = expand(y)
__global__ __launch_bounds__(256) void k_gn(const float* __restrict__ Y2,
    const float* __restrict__ ybar, const float* __restrict__ ew,
    const float* __restrict__ eb, float* __restrict__ stats){
  __shared__ float wsm[64*65];
  __shared__ float red[512];
  int t=threadIdx.x;
  int bg=blockIdx.x, b=bg>>2, g=bg&3;
  for (int i=t;i<4096;i+=256){
    int c=i>>6, m=i&63;
    wsm[c*65+m] = ew[(((size_t)g<<6)+c)*64 + m];
  }
  __syncthreads();
  int c = t&63, qm = t>>6;
  const float* wv = &wsm[c*65];
  const float* Y2b = Y2 + ((size_t)b<<12);
  const float* yb = ybar + (b<<6);
  float q=0.f, sbp=0.f;
  for (int m=qm*16; m<qm*16+16; m++){
    const float* row = Y2b + (m<<6);
    float ym=0.f;
    for (int nn=0;nn<64;nn+=4){
      float4 r4=*(const float4*)(row+nn);
      ym += r4.x*wv[nn] + r4.y*wv[nn+1] + r4.z*wv[nn+2] + r4.w*wv[nn+3];
    }
    q += ym*wv[m];
    sbp += wv[m]*yb[m];
  }
  float bias = eb[(g<<6)+c];
  float pz  = sbp + (qm==0 ? 16384.f*bias : 0.f);
  float pz2 = q + 2.f*bias*sbp + (qm==0 ? 16384.f*bias*bias : 0.f);
  red[t]=pz; red[256+t]=pz2;
  __syncthreads();
  for (int s=128;s>0;s>>=1){
    if (t<s){ red[t]+=red[t+s]; red[256+t]+=red[256+t+s]; }
    __syncthreads();
  }
  if (t==0){
    const float N=64.f*16384.f;
    float mu = red[0]/N;
    float var = red[256]/N - mu*mu;
    stats[bg*2]=mu; stats[bg*2+1]=rsqrtf(var+1e-5f);
  }
}

// ---- final MFMA: z = expand(y_bf16), GN apply + gelu + residual -> NCHW.
// 64-px tiles (grid 256x8), 8 KB LDS, pure-copy swizzled staging.
__global__ __launch_bounds__(256) void k_final(const ushort* __restrict__ y,
    const ushort* __restrict__ ewb, const float* __restrict__ eb,
    const float* __restrict__ stats, const float* __restrict__ gamma,
    const float* __restrict__ beta, const float* __restrict__ feat,
    float* __restrict__ out){
  __shared__ ushort A[64*64];            // 8 KB bf16 y-tile
  int t = threadIdx.x;
  int b = blockIdx.y, p0 = blockIdx.x*64;
  int lane = t & 63, w = t >> 6, ln = lane & 15, qd = lane >> 4;
  {
    int px = t>>2, ch0 = (t&3)*16;       // 16 ch = 32 B per thread
    const uint4* yp = (const uint4*)(y + ((size_t)(b*HW + p0 + px))*64 + ch0);
    uint4 v0 = yp[0], v1 = yp[1];
    int c16 = ch0 >> 3;                  // 16B-chunk index
    char* Ab = (char*)A + px*128;
    *(uint4*)(Ab + ((c16  )^(px&7))*16) = v0;
    *(uint4*)(Ab + ((c16+1)^(px&7))*16) = v1;
  }
  __syncthreads();
  float mu = stats[((b<<2)+w)*2], rstd = stats[((b<<2)+w)*2+1];
  const float* fb = feat + (size_t)b*CC*HW + p0;
  float* ob = out + (size_t)b*CC*HW + p0;
  for (int nt=0;nt<4;nt++){
    int nch = (w<<6) + (nt<<4) + ln;
    const ushort* wb = ewb + (size_t)nch*64 + (qd<<3);
    bf16x8 b0 = *(const bf16x8*)wb;
    bf16x8 b1 = *(const bf16x8*)(wb + 32);
    f32x4 acc[4];
    #pragma unroll
    for (int pt=0;pt<4;pt++) acc[pt] = (f32x4){0.f,0.f,0.f,0.f};
    #pragma unroll
    for (int pt=0;pt<4;pt++){
      int m = (pt<<4) + ln;
      int ch0 = qd ^ (m&7), ch1 = (4+qd) ^ (m&7);
      bf16x8 a0 = *(bf16x8*)(A + (m<<6) + (ch0<<3));
      acc[pt] = __builtin_amdgcn_mfma_f32_16x16x32_bf16(a0, b0, acc[pt], 0,0,0);
      bf16x8 a1 = *(bf16x8*)(A + (m<<6) + (ch1<<3));
      acc[pt] = __builtin_amdgcn_mfma_f32_16x16x32_bf16(a1, b1, acc[pt], 0,0,0);
    }
    float bias = eb[nch];
    float ga = gamma[nch], be = beta[nch];
    float gr = rstd*ga;
    float ofs = (bias - mu)*gr + be;     // z*gr + ofs == (z+bias-mu)*rstd*ga + be
    const float* frow = fb + (size_t)nch*HW;
    float* orow = ob + (size_t)nch*HW;
    #pragma unroll
    for (int pt=0;pt<4;pt++){
      int px = (pt<<4) + (qd<<2);
      float4 f = *(const float4*)(frow + px);
      float4 o;
      o.x = f.x + gelu_f(acc[pt][0]*gr + ofs);
      o.y = f.y + gelu_f(acc[pt][1]*gr + ofs);
      o.z = f.z + gelu_f(acc[pt][2]*gr + ofs);
      o.w = f.w + gelu_f(acc[pt][3]*gr + ofs);
      *(float4*)(orow + px) = o;
    }
  }
}

extern "C" void kernel_launch(void* const* d_in, const int* in_sizes, int n_in,
                              void* d_out, int out_size, void* d_ws, size_t ws_size,
                              hipStream_t stream){
  const float* feat = (const float*)d_in[0];
  const float* wind = (const float*)d_in[1];
  const float* cw   = (const float*)d_in[2];
  const float* cb   = (const float*)d_in[3];
  const float* w1   = (const float*)d_in[4];
  const float* b1   = (const float*)d_in[5];
  const float* w2   = (const float*)d_in[6];
  const float* b2   = (const float*)d_in[7];
  const float* dw   = (const float*)d_in[8];
  const float* db   = (const float*)d_in[9];
  const float* ew   = (const float*)d_in[10];
  const float* ebias= (const float*)d_in[11];
  const float* gg   = (const float*)d_in[12];
  const float* gb   = (const float*)d_in[13];
  float* ws = (float*)d_ws;
  float* x_nhwc   = ws;                    // 8388608 floats
  ushort* y_bf16  = (ushort*)(ws + 8388608);  // 8388608 ushorts (16.7 MB)
  float* h_nhwc   = ws + 16777216;         // 4194304 (reused as partY2 after off2)
  float* off_nhwc = ws + 20971520;         // 2359296 (reused as partYb after deform)
  ushort* bt      = (ushort*)(ws + 23330816); // 36864 ush
  ushort* cwb     = (ushort*)(ws + 23349248); // 16384 ush
  ushort* ewb     = (ushort*)(ws + 23357440); // 16384 ush
  float* Y2       = ws + 23365632;         // 32768
  float* ybar     = ws + 23398400;         // 512
  float* stats    = ws + 23398912;         // 64
  float* partY2   = h_nhwc;                // 1024*4096 floats, dead after off2
  float* partYb   = off_nhwc;              // 1024*64 floats, dead after deform
  k_prep<<<272,256,0,stream>>>(dw, cw, ew, bt, cwb, ewb);
  k_compress<<<dim3(128,8),256,0,stream>>>(feat, cwb, cb, x_nhwc);
  k_off1<<<dim3(64,8),256,0,stream>>>(wind, w1, b1, h_nhwc);
  k_off2<<<dim3(64,8),256,0,stream>>>(h_nhwc, w2, b2, off_nhwc);
  k_deform<<<1024,256,0,stream>>>(x_nhwc, off_nhwc, bt, db, y_bf16);
  k_stats<<<dim3(128,8),256,0,stream>>>(y_bf16, partY2, partYb);
  k_reduce<<<dim3(5,8),256,0,stream>>>(partY2, partYb, Y2, ybar);
  k_gn<<<32,256,0,stream>>>(Y2, ybar, ew, ebias, stats);
  k_final<<<dim3(256,8),256,0,stream>>>(y_bf16, ewb, ebias, stats, gg, gb, feat, (float*)d_out);
}

// Round 6
// 506.928 us; speedup vs baseline: 1.4239x; 1.0043x over previous
//
#include <hip/hip_runtime.h>
#include <math.h>

// WindAdvectionBlock: B=8, C=256, H=W=128, mid=64
// compress(1x1,MFMA, nt feat loads) -> off1+gelu -> off2 -> deform(MFMA,
// coalesced gather, XCD-swizzled, bf16 y out, FUSED GN-stat partials) ->
// reduce -> gn -> final(MFMA expand+GN+gelu+residual, nt feat/out)

#define BB 8
#define CC 256
#define HW 16384
#define MID 64

typedef __attribute__((ext_vector_type(8))) short bf16x8;
typedef __attribute__((ext_vector_type(4))) float f32x4;

__device__ __forceinline__ float gelu_f(float v){
  return 0.5f*v*(1.0f + erff(v*0.7071067811865476f));
}
__device__ __forceinline__ unsigned f2bf(float f){
  union { float f; unsigned u; } v; v.f = f;
  unsigned u = v.u;
  u += 0x7fff + ((u >> 16) & 1);   // RNE
  return (u >> 16);
}
__device__ __forceinline__ float bf2f(unsigned u){
  union { unsigned u; float f; } v; v.u = u; return v.f;
}

// ---- prep: bt bf16 [9][64o][64c] from dw [64o][64c][9]; cwb bf16 [64o][256c];
//            ewb bf16 [256o][64c]
__global__ void k_prep(const float* __restrict__ dw, const float* __restrict__ cw,
                       const float* __restrict__ ew, ushort* __restrict__ bt,
                       ushort* __restrict__ cwb, ushort* __restrict__ ewb){
  int i = blockIdx.x*256 + threadIdx.x;
  if (i < 36864){
    int k = i >> 12, r = i & 4095;
    int o = r >> 6, c = r & 63;
    bt[i] = (ushort)f2bf(dw[(o*64+c)*9 + k]);
  }
  int j = i - 36864;
  if (j >= 0 && j < 16384) cwb[j] = (ushort)f2bf(cw[j]);
  int l = i - 53248;
  if (l >= 0 && l < 16384) ewb[l] = (ushort)f2bf(ew[l]);
}

// ---- compress 1x1 via MFMA: feat NCHW -> x NHWC [b][p][64]
__global__ __launch_bounds__(256) void k_compress(const float* __restrict__ feat,
    const ushort* __restrict__ cwb, const float* __restrict__ cb, float* __restrict__ xo){
  __shared__ ushort A[128*64];           // 16 KB, [px][64c] bf16, 16B chunks xor px&7
  int t = threadIdx.x;
  int b = blockIdx.y, p0 = blockIdx.x*128;
  int lane = t & 63, w = t >> 6, ln = lane & 15, qd = lane >> 4;
  int n = (w<<4) + ln;                   // out channel
  int cg = t >> 4, pxg = t & 15;         // staging: 4-ch group, 8-px group
  f32x4 acc[8];
  #pragma unroll
  for (int pt=0;pt<8;pt++) acc[pt] = (f32x4){0.f,0.f,0.f,0.f};
  for (int kt=0;kt<4;kt++){
    const float* fb = feat + ((size_t)(b*CC + kt*64 + cg*4))*HW + p0 + pxg*8;
    f32x4 v0[4], v1[4];
    #pragma unroll
    for (int i=0;i<4;i++){
      v0[i] = __builtin_nontemporal_load((const f32x4*)(fb + (size_t)i*HW));
      v1[i] = __builtin_nontemporal_load((const f32x4*)(fb + (size_t)i*HW + 4));
    }
    __syncthreads();                     // prev tile's readers done
    #pragma unroll
    for (int j=0;j<8;j++){
      int px = pxg*8 + j;
      float e0 = (j<4)? v0[0][j&3] : v1[0][j&3];
      float e1 = (j<4)? v0[1][j&3] : v1[1][j&3];
      float e2 = (j<4)? v0[2][j&3] : v1[2][j&3];
      float e3 = (j<4)? v0[3][j&3] : v1[3][j&3];
      unsigned lo = f2bf(e0) | (f2bf(e1)<<16);
      unsigned hi = f2bf(e2) | (f2bf(e3)<<16);
      int chunk = (cg>>1) ^ (px&7);
      *(uint2*)((char*)A + px*128 + chunk*16 + (cg&1)*8) = make_uint2(lo,hi);
    }
    __syncthreads();
    const ushort* wb = cwb + (size_t)n*256 + kt*64 + (qd<<3);
    bf16x8 b0 = *(const bf16x8*)wb;
    bf16x8 b1 = *(const bf16x8*)(wb + 32);
    #pragma unroll
    for (int pt=0;pt<8;pt++){
      int m = (pt<<4) + ln;
      int ch0 = qd ^ (m&7), ch1 = (4+qd) ^ (m&7);
      bf16x8 a0 = *(bf16x8*)(A + (m<<6) + (ch0<<3));
      acc[pt] = __builtin_amdgcn_mfma_f32_16x16x32_bf16(a0, b0, acc[pt], 0,0,0);
      bf16x8 a1 = *(bf16x8*)(A + (m<<6) + (ch1<<3));
      acc[pt] = __builtin_amdgcn_mfma_f32_16x16x32_bf16(a1, b1, acc[pt], 0,0,0);
    }
  }
  float bias = cb[n];
  float* xp = xo + ((size_t)(b*HW + p0))*64 + n;
  #pragma unroll
  for (int pt=0;pt<8;pt++){
    #pragma unroll
    for (int rg=0;rg<4;rg++){
      int px = (pt<<4) + (qd<<2) + rg;
      xp[(size_t)px*64] = acc[pt][rg] + bias;
    }
  }
}

// ---- off1: wind [b][2][H][W] -> h NHWC [b][p][32], conv3x3 pad1 + gelu
__global__ __launch_bounds__(256) void k_off1(const float* __restrict__ wind,
    const float* __restrict__ w1, const float* __restrict__ b1, float* __restrict__ ho){
  __shared__ float wl[576];
  int t=threadIdx.x;
  for (int i=t;i<576;i+=256) wl[i]=w1[i];
  __syncthreads();
  int b=blockIdx.y; int p=blockIdx.x*256+t;
  int y=p>>7, x=p&127;
  float tap[18];
  #pragma unroll
  for (int c=0;c<2;c++){
    #pragma unroll
    for (int ki=0;ki<3;ki++){
      #pragma unroll
      for (int kj=0;kj<3;kj++){
        int yy=y+ki-1, xx=x+kj-1;
        float v=0.f;
        if ((unsigned)yy<128u && (unsigned)xx<128u)
          v = wind[((size_t)b*2+c)*HW + (yy<<7)+xx];
        tap[c*9+ki*3+kj]=v;
      }
    }
  }
  float outv[32];
  #pragma unroll
  for (int o=0;o<32;o++){
    float a=b1[o];
    #pragma unroll
    for (int i=0;i<18;i++) a += tap[i]*wl[o*18+i];
    outv[o]=gelu_f(a);
  }
  float* hp = ho + ((size_t)(b*HW+p))*32;
  #pragma unroll
  for (int o=0;o<32;o+=4) *(float4*)(hp+o)=make_float4(outv[o],outv[o+1],outv[o+2],outv[o+3]);
}

// ---- off2: h NHWC [b][p][32] -> offsets NHWC [b][p][18], conv3x3 pad1
__global__ __launch_bounds__(256) void k_off2(const float* __restrict__ h,
    const float* __restrict__ w2, const float* __restrict__ b2, float* __restrict__ oo){
  __shared__ float wl[9*18*32];
  int t=threadIdx.x;
  for (int i=t;i<5184;i+=256){
    int k=i/576; int r=i-k*576; int o=r>>5; int c=r&31;
    wl[i] = w2[(o*32+c)*9+k];
  }
  __syncthreads();
  int b=blockIdx.y; int p=blockIdx.x*256+t;
  int y=p>>7, x=p&127;
  float acc[18];
  #pragma unroll
  for (int o=0;o<18;o++) acc[o]=b2[o];
  for (int ki=0;ki<3;ki++){
    for (int kj=0;kj<3;kj++){
      int k = ki*3+kj;
      int yy=y+ki-1, xx=x+kj-1;
      float4 hv[8];
      if ((unsigned)yy<128u && (unsigned)xx<128u){
        const float* hp = h + ((size_t)(b*HW) + (yy<<7)+xx)*32;
        #pragma unroll
        for (int q=0;q<8;q++) hv[q]=*(const float4*)(hp+q*4);
      } else {
        #pragma unroll
        for (int q=0;q<8;q++) hv[q]=make_float4(0.f,0.f,0.f,0.f);
      }
      const float* wk = &wl[k*576];
      #pragma unroll
      for (int o=0;o<18;o++){
        float a=acc[o];
        #pragma unroll
        for (int q=0;q<8;q++){
          float4 w4 = *(const float4*)(wk + o*32 + q*4);
          a += hv[q].x*w4.x + hv[q].y*w4.y + hv[q].z*w4.z + hv[q].w*w4.w;
        }
        acc[o]=a;
      }
    }
  }
  float* op = oo + ((size_t)(b*HW+p))*18;
  #pragma unroll
  for (int o=0;o<18;o+=2) *(float2*)(op+o)=make_float2(acc[o],acc[o+1]);
}

// ---- deform conv MFMA + FUSED GN-stat partials.
// Grid 1024 linear: b = blk&7 (XCD locality), r = blk>>3.
__global__ __launch_bounds__(256) void k_deform(
    const float* __restrict__ x, const float* __restrict__ off,
    const ushort* __restrict__ bt, const float* __restrict__ db,
    ushort* __restrict__ yo, float* __restrict__ partY2,
    float* __restrict__ partYb){
  __shared__ ushort A[128*64];           // 16 KB
  __shared__ float offs[128*18];         // 9 KB
  int t = threadIdx.x;
  int blk = blockIdx.x;
  int b = blk & 7, r = blk >> 3;
  int p0 = r*128;
  const float* offg = off + ((size_t)(b*HW + p0))*18;
  for (int i=t;i<576;i+=256)
    *(float4*)(offs + i*4) = *(const float4*)(offg + i*4);
  __syncthreads();
  int lane = t & 63, w = t >> 6, ln = lane & 15, qd = lane >> 4;
  int n = (w<<4) + ln;
  const float* xb = x + (size_t)b*HW*64;
  f32x4 acc[8];
  #pragma unroll
  for (int pt=0;pt<8;pt++) acc[pt] = (f32x4){0.f,0.f,0.f,0.f};

  for (int k=0;k<9;k++){
    int ki = k/3, kj = k - ki*3;
    const ushort* btk = bt + (size_t)(((k<<6) + n)<<6) + (qd<<3);
    bf16x8 bf0 = *(const bf16x8*)btk;
    bf16x8 bf1 = *(const bf16x8*)(btk + 32);
    __syncthreads();                     // prev tap's MFMA reads done
    #pragma unroll
    for (int pp=0;pp<8;pp++){
      int p = (w<<5) + (pp<<2) + qd;     // pixel (x-coord) 0..127
      float2 dd = *(const float2*)(offs + p*18 + 2*k);
      float py  = dd.x + (float)(r + ki - 1);
      float pxs = dd.y + (float)(p + kj - 1);
      float y0f = floorf(py), x0f = floorf(pxs);
      float fy = py - y0f, fx = pxs - x0f;
      int y0 = (int)y0f, x0 = (int)x0f;
      float w00=(1.f-fy)*(1.f-fx), w01=(1.f-fy)*fx, w10=fy*(1.f-fx), w11=fy*fx;
      bool v0=((unsigned)y0<128u), v1=((unsigned)(y0+1)<128u);
      bool u0=((unsigned)x0<128u), u1=((unsigned)(x0+1)<128u);
      w00 = (v0&&u0)? w00 : 0.f;  w01 = (v0&&u1)? w01 : 0.f;
      w10 = (v1&&u0)? w10 : 0.f;  w11 = (v1&&u1)? w11 : 0.f;
      int y0c = min(max(y0,0),127), y1c = min(max(y0+1,0),127);
      int x0c = min(max(x0,0),127), x1c = min(max(x0+1,0),127);
      int cofs = (ln<<2);
      const float4* r00 = (const float4*)(xb + (size_t)y0c*8192 + x0c*64 + cofs);
      const float4* r01 = (const float4*)(xb + (size_t)y0c*8192 + x1c*64 + cofs);
      const float4* r10 = (const float4*)(xb + (size_t)y1c*8192 + x0c*64 + cofs);
      const float4* r11 = (const float4*)(xb + (size_t)y1c*8192 + x1c*64 + cofs);
      float4 a00=*r00, a01=*r01, a10=*r10, a11=*r11;
      float4 s;
      s.x = a00.x*w00 + a01.x*w01 + a10.x*w10 + a11.x*w11;
      s.y = a00.y*w00 + a01.y*w01 + a10.y*w10 + a11.y*w11;
      s.z = a00.z*w00 + a01.z*w01 + a10.z*w10 + a11.z*w11;
      s.w = a00.w*w00 + a01.w*w01 + a10.w*w10 + a11.w*w11;
      unsigned lo = f2bf(s.x) | (f2bf(s.y)<<16);
      unsigned hi = f2bf(s.z) | (f2bf(s.w)<<16);
      int chunk = (ln>>1) ^ (p&7);
      *(uint2*)((char*)A + p*128 + chunk*16 + (ln&1)*8) = make_uint2(lo,hi);
    }
    __syncthreads();                     // A tile ready
    #pragma unroll
    for (int pt=0;pt<8;pt++){
      int m = (pt<<4) + ln;
      int ch0 = qd ^ (m&7), ch1 = (4+qd) ^ (m&7);
      bf16x8 a0 = *(bf16x8*)(A + (m<<6) + (ch0<<3));
      acc[pt] = __builtin_amdgcn_mfma_f32_16x16x32_bf16(a0, bf0, acc[pt], 0,0,0);
      bf16x8 a1 = *(bf16x8*)(A + (m<<6) + (ch1<<3));
      acc[pt] = __builtin_amdgcn_mfma_f32_16x16x32_bf16(a1, bf1, acc[pt], 0,0,0);
    }
  }
  __syncthreads();                       // all MFMA reads of A done
  float bias = db[n];
  // repack y tile as bf16 into A[px*64 + n]; accumulate ybar from f32 regs
  float ysum = 0.f;
  #pragma unroll
  for (int pt=0;pt<8;pt++){
    #pragma unroll
    for (int rg=0;rg<4;rg++){
      int px = (pt<<4) + (qd<<2) + rg;
      float yv = acc[pt][rg] + bias;
      A[(px<<6) + n] = (ushort)f2bf(yv);
      ysum += yv;
    }
  }
  // reduce over the 4 qd-groups holding the same channel n
  ysum += __shfl_xor(ysum, 16, 64);
  ysum += __shfl_xor(ysum, 32, 64);
  __syncthreads();
  // coalesced y store: 1024 uint4, 4 per thread
  uint4* yq = (uint4*)(yo + ((size_t)(b*HW + p0))*64);
  const uint4* As = (const uint4*)A;
  #pragma unroll
  for (int q=0;q<4;q++) yq[t + q*256] = As[t + q*256];
  if (qd == 0) partYb[((size_t)(b*128+r))*64 + n] = ysum;
  // ---- fused stats: partial Y2 (64x64) outer product from bf16 A tile.
  // ib/jb reads are same-address within 16-lane groups -> LDS broadcast.
  int ib = t & 15, jb = t >> 4;
  float sacc[4][4];
  #pragma unroll
  for (int a=0;a<4;a++)
    #pragma unroll
    for (int c=0;c<4;c++) sacc[a][c]=0.f;
  for (int p=0;p<128;p++){
    uint2 ui = *(const uint2*)(A + (p<<6) + (ib<<2));
    uint2 uj = *(const uint2*)(A + (p<<6) + (jb<<2));
    float fi[4] = { bf2f(ui.x<<16), bf2f(ui.x&0xffff0000u),
                    bf2f(ui.y<<16), bf2f(ui.y&0xffff0000u) };
    float fj[4] = { bf2f(uj.x<<16), bf2f(uj.x&0xffff0000u),
                    bf2f(uj.y<<16), bf2f(uj.y&0xffff0000u) };
    #pragma unroll
    for (int a=0;a<4;a++)
      #pragma unroll
      for (int c=0;c<4;c++) sacc[a][c] += fi[a]*fj[c];
  }
  float* pb = partY2 + ((size_t)(b*128+r))*4096;
  #pragma unroll
  for (int a=0;a<4;a++)
    *(float4*)(pb + (ib*4+a)*64 + jb*4) =
        make_float4(sacc[a][0],sacc[a][1],sacc[a][2],sacc[a][3]);
}

// ---- stats stage B: fold 128 partials per batch into Y2 / ybar (coalesced).
__global__ __launch_bounds__(256) void k_reduce(const float* __restrict__ partY2,
    const float* __restrict__ partYb, float* __restrict__ Y2,
    float* __restrict__ ybar){
  int t=threadIdx.x; int b=blockIdx.y;
  if (blockIdx.x < 4){
    int e = (blockIdx.x*256 + t)*4;
    const float* p = partY2 + ((size_t)b*128)*4096 + e;
    float4 s=make_float4(0.f,0.f,0.f,0.f);
    for (int r=0;r<128;r++){
      float4 v=*(const float4*)(p+(size_t)r*4096);
      s.x+=v.x; s.y+=v.y; s.z+=v.z; s.w+=v.w;
    }
    *(float4*)(Y2+((size_t)b<<12)+e)=s;
  } else if (t < 16){
    int e = t*4;
    const float* p = partYb + (size_t)b*8192 + e;
    float4 s=make_float4(0.f,0.f,0.f,0.f);
    for (int r=0;r<128;r++){
      float4 v=*(const float4*)(p+r*64);
      s.x+=v.x; s.y+=v.y; s.z+=v.z; s.w+=v.w;
    }
    *(float4*)(ybar+(b<<6)+e)=s;
  }
}

// ---- analytic GN stats per (b,g): mu, rstd of z = expand(y)
__global__ __launch_bounds__(256) void k_gn(const float* __restrict__ Y2,
    const float* __restrict__ ybar, const float* __restrict__ ew,
    const float* __restrict__ eb, float* __restrict__ stats){
  __shared__ float wsm[64*65];
  __shared__ float red[512];
  int t=threadIdx.x;
  int bg=blockIdx.x, b=bg>>2, g=bg&3;
  for (int i=t;i<4096;i+=256){
    int c=i>>6, m=i&63;
    wsm[c*65+m] = ew[(((size_t)g<<6)+c)*64 + m];
  }
  __syncthreads();
  int c = t&63, qm = t>>6;
  const float* wv = &wsm[c*65];
  const float* Y2b = Y2 + ((size_t)b<<12);
  const float* yb = ybar + (b<<6);
  float q=0.f, sbp=0.f;
  for (int m=qm*16; m<qm*16+16; m++){
    const float* row = Y2b + (m<<6);
    float ym=0.f;
    for (int nn=0;nn<64;nn+=4){
      float4 r4=*(const float4*)(row+nn);
      ym += r4.x*wv[nn] + r4.y*wv[nn+1] + r4.z*wv[nn+2] + r4.w*wv[nn+3];
    }
    q += ym*wv[m];
    sbp += wv[m]*yb[m];
  }
  float bias = eb[(g<<6)+c];
  float pz  = sbp + (qm==0 ? 16384.f*bias : 0.f);
  float pz2 = q + 2.f*bias*sbp + (qm==0 ? 16384.f*bias*bias : 0.f);
  red[t]=pz; red[256+t]=pz2;
  __syncthreads();
  for (int s=128;s>0;s>>=1){
    if (t<s){ red[t]+=red[t+s]; red[256+t]+=red[256+t+s]; }
    __syncthreads();
  }
  if (t==0){
    const float N=64.f*16384.f;
    float mu = red[0]/N;
    float var = red[256]/N - mu*mu;
    stats[bg*2]=mu; stats[bg*2+1]=rsqrtf(var+1e-5f);
  }
}

// ---- final MFMA: z = expand(y_bf16), GN apply + gelu + residual -> NCHW.
// 64-px tiles (grid 256x8), 8 KB LDS; nontemporal feat loads / out stores.
__global__ __launch_bounds__(256) void k_final(const ushort* __restrict__ y,
    const ushort* __restrict__ ewb, const float* __restrict__ eb,
    const float* __restrict__ stats, const float* __restrict__ gamma,
    const float* __restrict__ beta, const float* __restrict__ feat,
    float* __restrict__ out){
  __shared__ ushort A[64*64];            // 8 KB bf16 y-tile
  int t = threadIdx.x;
  int b = blockIdx.y, p0 = blockIdx.x*64;
  int lane = t & 63, w = t >> 6, ln = lane & 15, qd = lane >> 4;
  {
    int px = t>>2, ch0 = (t&3)*16;       // 16 ch = 32 B per thread
    const uint4* yp = (const uint4*)(y + ((size_t)(b*HW + p0 + px))*64 + ch0);
    uint4 v0 = yp[0], v1 = yp[1];
    int c16 = ch0 >> 3;                  // 16B-chunk index
    char* Ab = (char*)A + px*128;
    *(uint4*)(Ab + ((c16  )^(px&7))*16) = v0;
    *(uint4*)(Ab + ((c16+1)^(px&7))*16) = v1;
  }
  __syncthreads();
  float mu = stats[((b<<2)+w)*2], rstd = stats[((b<<2)+w)*2+1];
  const float* fb = feat + (size_t)b*CC*HW + p0;
  float* ob = out + (size_t)b*CC*HW + p0;
  for (int nt=0;nt<4;nt++){
    int nch = (w<<6) + (nt<<4) + ln;
    const ushort* wb = ewb + (size_t)nch*64 + (qd<<3);
    bf16x8 b0 = *(const bf16x8*)wb;
    bf16x8 b1 = *(const bf16x8*)(wb + 32);
    f32x4 acc[4];
    #pragma unroll
    for (int pt=0;pt<4;pt++) acc[pt] = (f32x4){0.f,0.f,0.f,0.f};
    #pragma unroll
    for (int pt=0;pt<4;pt++){
      int m = (pt<<4) + ln;
      int ch0 = qd ^ (m&7), ch1 = (4+qd) ^ (m&7);
      bf16x8 a0 = *(bf16x8*)(A + (m<<6) + (ch0<<3));
      acc[pt] = __builtin_amdgcn_mfma_f32_16x16x32_bf16(a0, b0, acc[pt], 0,0,0);
      bf16x8 a1 = *(bf16x8*)(A + (m<<6) + (ch1<<3));
      acc[pt] = __builtin_amdgcn_mfma_f32_16x16x32_bf16(a1, b1, acc[pt], 0,0,0);
    }
    float bias = eb[nch];
    float ga = gamma[nch], be = beta[nch];
    float gr = rstd*ga;
    float ofs = (bias - mu)*gr + be;     // z*gr + ofs == (z+bias-mu)*rstd*ga + be
    const float* frow = fb + (size_t)nch*HW;
    float* orow = ob + (size_t)nch*HW;
    #pragma unroll
    for (int pt=0;pt<4;pt++){
      int px = (pt<<4) + (qd<<2);
      f32x4 f = __builtin_nontemporal_load((const f32x4*)(frow + px));
      f32x4 o;
      o[0] = f[0] + gelu_f(acc[pt][0]*gr + ofs);
      o[1] = f[1] + gelu_f(acc[pt][1]*gr + ofs);
      o[2] = f[2] + gelu_f(acc[pt][2]*gr + ofs);
      o[3] = f[3] + gelu_f(acc[pt][3]*gr + ofs);
      __builtin_nontemporal_store(o, (f32x4*)(orow + px));
    }
  }
}

extern "C" void kernel_launch(void* const* d_in, const int* in_sizes, int n_in,
                              void* d_out, int out_size, void* d_ws, size_t ws_size,
                              hipStream_t stream){
  const float* feat = (const float*)d_in[0];
  const float* wind = (const float*)d_in[1];
  const float* cw   = (const float*)d_in[2];
  const float* cb   = (const float*)d_in[3];
  const float* w1   = (const float*)d_in[4];
  const float* b1   = (const float*)d_in[5];
  const float* w2   = (const float*)d_in[6];
  const float* b2   = (const float*)d_in[7];
  const float* dw   = (const float*)d_in[8];
  const float* db   = (const float*)d_in[9];
  const float* ew   = (const float*)d_in[10];
  const float* ebias= (const float*)d_in[11];
  const float* gg   = (const float*)d_in[12];
  const float* gb   = (const float*)d_in[13];
  float* ws = (float*)d_ws;
  float* x_nhwc   = ws;                    // 8388608 floats
  ushort* y_bf16  = (ushort*)(ws + 8388608);  // 8388608 ushorts (16.7 MB)
  float* h_nhwc   = ws + 16777216;         // 4194304 (reused as partY2 after off2)
  float* off_nhwc = ws + 20971520;         // 2359296 (reused as partYb after deform)
  ushort* bt      = (ushort*)(ws + 23330816); // 36864 ush
  ushort* cwb     = (ushort*)(ws + 23349248); // 16384 ush
  ushort* ewb     = (ushort*)(ws + 23357440); // 16384 ush
  float* Y2       = ws + 23365632;         // 32768
  float* ybar     = ws + 23398400;         // 512
  float* stats    = ws + 23398912;         // 64
  float* partY2   = h_nhwc;                // 1024*4096 floats, dead after off2
  float* partYb   = off_nhwc;              // 1024*64 floats, dead after deform's offs read
  k_prep<<<272,256,0,stream>>>(dw, cw, ew, bt, cwb, ewb);
  k_compress<<<dim3(128,8),256,0,stream>>>(feat, cwb, cb, x_nhwc);
  k_off1<<<dim3(64,8),256,0,stream>>>(wind, w1, b1, h_nhwc);
  k_off2<<<dim3(64,8),256,0,stream>>>(h_nhwc, w2, b2, off_nhwc);
  k_deform<<<1024,256,0,stream>>>(x_nhwc, off_nhwc, bt, db, y_bf16, partY2, partYb);
  k_reduce<<<dim3(5,8),256,0,stream>>>(partY2, partYb, Y2, ybar);
  k_gn<<<32,256,0,stream>>>(Y2, ybar, ew, ebias, stats);
  k_final<<<dim3(256,8),256,0,stream>>>(y_bf16, ewb, ebias, stats, gg, gb, feat, (float*)d_out);
}

// Round 7
// 488.066 us; speedup vs baseline: 1.4789x; 1.0386x over previous
//
#include <hip/hip_runtime.h>
#include <math.h>

// WindAdvectionBlock: B=8, C=256, H=W=128, mid=64
// compress(1x1,MFMA) -> off1+gelu -> off2 -> deform(MFMA, coalesced gather,
// XCD-swizzled, bf16 y out, FUSED GN-stat partials) -> reduce(4x split) ->
// gn -> final(MFMA expand+GN+gelu+residual, feat-prefetch, nt out stores)

#define BB 8
#define CC 256
#define HW 16384
#define MID 64

typedef __attribute__((ext_vector_type(8))) short bf16x8;
typedef __attribute__((ext_vector_type(4))) float f32x4;

__device__ __forceinline__ float gelu_f(float v){
  return 0.5f*v*(1.0f + erff(v*0.7071067811865476f));
}
__device__ __forceinline__ unsigned f2bf(float f){
  union { float f; unsigned u; } v; v.f = f;
  unsigned u = v.u;
  u += 0x7fff + ((u >> 16) & 1);   // RNE
  return (u >> 16);
}
__device__ __forceinline__ float bf2f(unsigned u){
  union { unsigned u; float f; } v; v.u = u; return v.f;
}

// ---- prep: bt bf16 [9][64o][64c] from dw [64o][64c][9]; cwb bf16 [64o][256c];
//            ewb bf16 [256o][64c]
__global__ void k_prep(const float* __restrict__ dw, const float* __restrict__ cw,
                       const float* __restrict__ ew, ushort* __restrict__ bt,
                       ushort* __restrict__ cwb, ushort* __restrict__ ewb){
  int i = blockIdx.x*256 + threadIdx.x;
  if (i < 36864){
    int k = i >> 12, r = i & 4095;
    int o = r >> 6, c = r & 63;
    bt[i] = (ushort)f2bf(dw[(o*64+c)*9 + k]);
  }
  int j = i - 36864;
  if (j >= 0 && j < 16384) cwb[j] = (ushort)f2bf(cw[j]);
  int l = i - 53248;
  if (l >= 0 && l < 16384) ewb[l] = (ushort)f2bf(ew[l]);
}

// ---- compress 1x1 via MFMA: feat NCHW -> x NHWC [b][p][64]
__global__ __launch_bounds__(256) void k_compress(const float* __restrict__ feat,
    const ushort* __restrict__ cwb, const float* __restrict__ cb, float* __restrict__ xo){
  __shared__ ushort A[128*64];           // 16 KB, [px][64c] bf16, 16B chunks xor px&7
  int t = threadIdx.x;
  int b = blockIdx.y, p0 = blockIdx.x*128;
  int lane = t & 63, w = t >> 6, ln = lane & 15, qd = lane >> 4;
  int n = (w<<4) + ln;                   // out channel
  int cg = t >> 4, pxg = t & 15;         // staging: 4-ch group, 8-px group
  f32x4 acc[8];
  #pragma unroll
  for (int pt=0;pt<8;pt++) acc[pt] = (f32x4){0.f,0.f,0.f,0.f};
  for (int kt=0;kt<4;kt++){
    const float* fb = feat + ((size_t)(b*CC + kt*64 + cg*4))*HW + p0 + pxg*8;
    float v[4][8];
    #pragma unroll
    for (int i=0;i<4;i++){
      *(float4*)&v[i][0] = *(const float4*)(fb + (size_t)i*HW);
      *(float4*)&v[i][4] = *(const float4*)(fb + (size_t)i*HW + 4);
    }
    __syncthreads();                     // prev tile's readers done
    #pragma unroll
    for (int j=0;j<8;j++){
      int px = pxg*8 + j;
      unsigned lo = f2bf(v[0][j]) | (f2bf(v[1][j])<<16);
      unsigned hi = f2bf(v[2][j]) | (f2bf(v[3][j])<<16);
      int chunk = (cg>>1) ^ (px&7);
      *(uint2*)((char*)A + px*128 + chunk*16 + (cg&1)*8) = make_uint2(lo,hi);
    }
    __syncthreads();
    const ushort* wb = cwb + (size_t)n*256 + kt*64 + (qd<<3);
    bf16x8 b0 = *(const bf16x8*)wb;
    bf16x8 b1 = *(const bf16x8*)(wb + 32);
    #pragma unroll
    for (int pt=0;pt<8;pt++){
      int m = (pt<<4) + ln;
      int ch0 = qd ^ (m&7), ch1 = (4+qd) ^ (m&7);
      bf16x8 a0 = *(bf16x8*)(A + (m<<6) + (ch0<<3));
      acc[pt] = __builtin_amdgcn_mfma_f32_16x16x32_bf16(a0, b0, acc[pt], 0,0,0);
      bf16x8 a1 = *(bf16x8*)(A + (m<<6) + (ch1<<3));
      acc[pt] = __builtin_amdgcn_mfma_f32_16x16x32_bf16(a1, b1, acc[pt], 0,0,0);
    }
  }
  float bias = cb[n];
  float* xp = xo + ((size_t)(b*HW + p0))*64 + n;
  #pragma unroll
  for (int pt=0;pt<8;pt++){
    #pragma unroll
    for (int rg=0;rg<4;rg++){
      int px = (pt<<4) + (qd<<2) + rg;
      xp[(size_t)px*64] = acc[pt][rg] + bias;
    }
  }
}

// ---- off1: wind [b][2][H][W] -> h NHWC [b][p][32], conv3x3 pad1 + gelu
__global__ __launch_bounds__(256) void k_off1(const float* __restrict__ wind,
    const float* __restrict__ w1, const float* __restrict__ b1, float* __restrict__ ho){
  __shared__ float wl[576];
  int t=threadIdx.x;
  for (int i=t;i<576;i+=256) wl[i]=w1[i];
  __syncthreads();
  int b=blockIdx.y; int p=blockIdx.x*256+t;
  int y=p>>7, x=p&127;
  float tap[18];
  #pragma unroll
  for (int c=0;c<2;c++){
    #pragma unroll
    for (int ki=0;ki<3;ki++){
      #pragma unroll
      for (int kj=0;kj<3;kj++){
        int yy=y+ki-1, xx=x+kj-1;
        float v=0.f;
        if ((unsigned)yy<128u && (unsigned)xx<128u)
          v = wind[((size_t)b*2+c)*HW + (yy<<7)+xx];
        tap[c*9+ki*3+kj]=v;
      }
    }
  }
  float outv[32];
  #pragma unroll
  for (int o=0;o<32;o++){
    float a=b1[o];
    #pragma unroll
    for (int i=0;i<18;i++) a += tap[i]*wl[o*18+i];
    outv[o]=gelu_f(a);
  }
  float* hp = ho + ((size_t)(b*HW+p))*32;
  #pragma unroll
  for (int o=0;o<32;o+=4) *(float4*)(hp+o)=make_float4(outv[o],outv[o+1],outv[o+2],outv[o+3]);
}

// ---- off2: h NHWC [b][p][32] -> offsets NHWC [b][p][18], conv3x3 pad1
__global__ __launch_bounds__(256) void k_off2(const float* __restrict__ h,
    const float* __restrict__ w2, const float* __restrict__ b2, float* __restrict__ oo){
  __shared__ float wl[9*18*32];
  int t=threadIdx.x;
  for (int i=t;i<5184;i+=256){
    int k=i/576; int r=i-k*576; int o=r>>5; int c=r&31;
    wl[i] = w2[(o*32+c)*9+k];
  }
  __syncthreads();
  int b=blockIdx.y; int p=blockIdx.x*256+t;
  int y=p>>7, x=p&127;
  float acc[18];
  #pragma unroll
  for (int o=0;o<18;o++) acc[o]=b2[o];
  for (int ki=0;ki<3;ki++){
    for (int kj=0;kj<3;kj++){
      int k = ki*3+kj;
      int yy=y+ki-1, xx=x+kj-1;
      float4 hv[8];
      if ((unsigned)yy<128u && (unsigned)xx<128u){
        const float* hp = h + ((size_t)(b*HW) + (yy<<7)+xx)*32;
        #pragma unroll
        for (int q=0;q<8;q++) hv[q]=*(const float4*)(hp+q*4);
      } else {
        #pragma unroll
        for (int q=0;q<8;q++) hv[q]=make_float4(0.f,0.f,0.f,0.f);
      }
      const float* wk = &wl[k*576];
      #pragma unroll
      for (int o=0;o<18;o++){
        float a=acc[o];
        #pragma unroll
        for (int q=0;q<8;q++){
          float4 w4 = *(const float4*)(wk + o*32 + q*4);
          a += hv[q].x*w4.x + hv[q].y*w4.y + hv[q].z*w4.z + hv[q].w*w4.w;
        }
        acc[o]=a;
      }
    }
  }
  float* op = oo + ((size_t)(b*HW+p))*18;
  #pragma unroll
  for (int o=0;o<18;o+=2) *(float2*)(op+o)=make_float2(acc[o],acc[o+1]);
}

// ---- deform conv MFMA + FUSED GN-stat partials.
// Grid 1024 linear: b = blk&7 (XCD locality), r = blk>>3.
__global__ __launch_bounds__(256) void k_deform(
    const float* __restrict__ x, const float* __restrict__ off,
    const ushort* __restrict__ bt, const float* __restrict__ db,
    ushort* __restrict__ yo, float* __restrict__ partY2,
    float* __restrict__ partYb){
  __shared__ ushort A[128*64];           // 16 KB
  __shared__ float offs[128*18];         // 9 KB
  int t = threadIdx.x;
  int blk = blockIdx.x;
  int b = blk & 7, r = blk >> 3;
  int p0 = r*128;
  const float* offg = off + ((size_t)(b*HW + p0))*18;
  for (int i=t;i<576;i+=256)
    *(float4*)(offs + i*4) = *(const float4*)(offg + i*4);
  __syncthreads();
  int lane = t & 63, w = t >> 6, ln = lane & 15, qd = lane >> 4;
  int n = (w<<4) + ln;
  const float* xb = x + (size_t)b*HW*64;
  f32x4 acc[8];
  #pragma unroll
  for (int pt=0;pt<8;pt++) acc[pt] = (f32x4){0.f,0.f,0.f,0.f};

  for (int k=0;k<9;k++){
    int ki = k/3, kj = k - ki*3;
    const ushort* btk = bt + (size_t)(((k<<6) + n)<<6) + (qd<<3);
    bf16x8 bf0 = *(const bf16x8*)btk;
    bf16x8 bf1 = *(const bf16x8*)(btk + 32);
    __syncthreads();                     // prev tap's MFMA reads done
    #pragma unroll
    for (int pp=0;pp<8;pp++){
      int p = (w<<5) + (pp<<2) + qd;     // pixel (x-coord) 0..127
      float2 dd = *(const float2*)(offs + p*18 + 2*k);
      float py  = dd.x + (float)(r + ki - 1);
      float pxs = dd.y + (float)(p + kj - 1);
      float y0f = floorf(py), x0f = floorf(pxs);
      float fy = py - y0f, fx = pxs - x0f;
      int y0 = (int)y0f, x0 = (int)x0f;
      float w00=(1.f-fy)*(1.f-fx), w01=(1.f-fy)*fx, w10=fy*(1.f-fx), w11=fy*fx;
      bool v0=((unsigned)y0<128u), v1=((unsigned)(y0+1)<128u);
      bool u0=((unsigned)x0<128u), u1=((unsigned)(x0+1)<128u);
      w00 = (v0&&u0)? w00 : 0.f;  w01 = (v0&&u1)? w01 : 0.f;
      w10 = (v1&&u0)? w10 : 0.f;  w11 = (v1&&u1)? w11 : 0.f;
      int y0c = min(max(y0,0),127), y1c = min(max(y0+1,0),127);
      int x0c = min(max(x0,0),127), x1c = min(max(x0+1,0),127);
      int cofs = (ln<<2);
      const float4* r00 = (const float4*)(xb + (size_t)y0c*8192 + x0c*64 + cofs);
      const float4* r01 = (const float4*)(xb + (size_t)y0c*8192 + x1c*64 + cofs);
      const float4* r10 = (const float4*)(xb + (size_t)y1c*8192 + x0c*64 + cofs);
      const float4* r11 = (const float4*)(xb + (size_t)y1c*8192 + x1c*64 + cofs);
      float4 a00=*r00, a01=*r01, a10=*r10, a11=*r11;
      float4 s;
      s.x = a00.x*w00 + a01.x*w01 + a10.x*w10 + a11.x*w11;
      s.y = a00.y*w00 + a01.y*w01 + a10.y*w10 + a11.y*w11;
      s.z = a00.z*w00 + a01.z*w01 + a10.z*w10 + a11.z*w11;
      s.w = a00.w*w00 + a01.w*w01 + a10.w*w10 + a11.w*w11;
      unsigned lo = f2bf(s.x) | (f2bf(s.y)<<16);
      unsigned hi = f2bf(s.z) | (f2bf(s.w)<<16);
      int chunk = (ln>>1) ^ (p&7);
      *(uint2*)((char*)A + p*128 + chunk*16 + (ln&1)*8) = make_uint2(lo,hi);
    }
    __syncthreads();                     // A tile ready
    #pragma unroll
    for (int pt=0;pt<8;pt++){
      int m = (pt<<4) + ln;
      int ch0 = qd ^ (m&7), ch1 = (4+qd) ^ (m&7);
      bf16x8 a0 = *(bf16x8*)(A + (m<<6) + (ch0<<3));
      acc[pt] = __builtin_amdgcn_mfma_f32_16x16x32_bf16(a0, bf0, acc[pt], 0,0,0);
      bf16x8 a1 = *(bf16x8*)(A + (m<<6) + (ch1<<3));
      acc[pt] = __builtin_amdgcn_mfma_f32_16x16x32_bf16(a1, bf1, acc[pt], 0,0,0);
    }
  }
  __syncthreads();                       // all MFMA reads of A done
  float bias = db[n];
  // repack y tile as bf16 into A[px*64 + n]; accumulate ybar from f32 regs
  float ysum = 0.f;
  #pragma unroll
  for (int pt=0;pt<8;pt++){
    #pragma unroll
    for (int rg=0;rg<4;rg++){
      int px = (pt<<4) + (qd<<2) + rg;
      float yv = acc[pt][rg] + bias;
      A[(px<<6) + n] = (ushort)f2bf(yv);
      ysum += yv;
    }
  }
  // reduce over the 4 qd-groups holding the same channel n
  ysum += __shfl_xor(ysum, 16, 64);
  ysum += __shfl_xor(ysum, 32, 64);
  __syncthreads();
  // coalesced y store: 1024 uint4, 4 per thread
  uint4* yq = (uint4*)(yo + ((size_t)(b*HW + p0))*64);
  const uint4* As = (const uint4*)A;
  #pragma unroll
  for (int q=0;q<4;q++) yq[t + q*256] = As[t + q*256];
  if (qd == 0) partYb[((size_t)(b*128+r))*64 + n] = ysum;
  // ---- fused stats: partial Y2 (64x64) outer product from bf16 A tile.
  // ib/jb reads are same-address within 16-lane groups -> LDS broadcast.
  int ib = t & 15, jb = t >> 4;
  float sacc[4][4];
  #pragma unroll
  for (int a=0;a<4;a++)
    #pragma unroll
    for (int c=0;c<4;c++) sacc[a][c]=0.f;
  for (int p=0;p<128;p++){
    uint2 ui = *(const uint2*)(A + (p<<6) + (ib<<2));
    uint2 uj = *(const uint2*)(A + (p<<6) + (jb<<2));
    float fi[4] = { bf2f(ui.x<<16), bf2f(ui.x&0xffff0000u),
                    bf2f(ui.y<<16), bf2f(ui.y&0xffff0000u) };
    float fj[4] = { bf2f(uj.x<<16), bf2f(uj.x&0xffff0000u),
                    bf2f(uj.y<<16), bf2f(uj.y&0xffff0000u) };
    #pragma unroll
    for (int a=0;a<4;a++)
      #pragma unroll
      for (int c=0;c<4;c++) sacc[a][c] += fi[a]*fj[c];
  }
  float* pb = partY2 + ((size_t)(b*128+r))*4096;
  #pragma unroll
  for (int a=0;a<4;a++)
    *(float4*)(pb + (ib*4+a)*64 + jb*4) =
        make_float4(sacc[a][0],sacc[a][1],sacc[a][2],sacc[a][3]);
}

// ---- stats stage B: fold 128 partials into 4 quarter-partials (grid 17x8).
// blockIdx.x<16: eq = x>>2 (1024-elem slice), rq = x&3 (32 r's) -> YQ[b][rq].
__global__ __launch_bounds__(256) void k_reduce(const float* __restrict__ partY2,
    const float* __restrict__ partYb, float* __restrict__ YQ,
    float* __restrict__ ybar){
  int t=threadIdx.x; int b=blockIdx.y;
  if (blockIdx.x < 16){
    int eq = blockIdx.x >> 2, rq = blockIdx.x & 3;
    int e = (eq*256 + t)*4;
    const float* p = partY2 + ((size_t)(b*128 + rq*32))*4096 + e;
    float4 s=make_float4(0.f,0.f,0.f,0.f);
    for (int r=0;r<32;r++){
      float4 v=*(const float4*)(p+(size_t)r*4096);
      s.x+=v.x; s.y+=v.y; s.z+=v.z; s.w+=v.w;
    }
    *(float4*)(YQ + (((size_t)(b*4 + rq))<<12) + e)=s;
  } else if (t < 16){
    int e = t*4;
    const float* p = partYb + (size_t)b*8192 + e;
    float4 s=make_float4(0.f,0.f,0.f,0.f);
    for (int r=0;r<128;r++){
      float4 v=*(const float4*)(p+r*64);
      s.x+=v.x; s.y+=v.y; s.z+=v.z; s.w+=v.w;
    }
    *(float4*)(ybar+(b<<6)+e)=s;
  }
}

// ---- analytic GN stats per (b,g): mu, rstd of z = expand(y)
// Y2 row = sum of 4 quarter-partials YQ[b][0..3].
__global__ __launch_bounds__(256) void k_gn(const float* __restrict__ YQ,
    const float* __restrict__ ybar, const float* __restrict__ ew,
    const float* __restrict__ eb, float* __restrict__ stats){
  __shared__ float wsm[64*65];
  __shared__ float red[512];
  int t=threadIdx.x;
  int bg=blockIdx.x, b=bg>>2, g=bg&3;
  for (int i=t;i<4096;i+=256){
    int c=i>>6, m=i&63;
    wsm[c*65+m] = ew[(((size_t)g<<6)+c)*64 + m];
  }
  __syncthreads();
  int c = t&63, qm = t>>6;
  const float* wv = &wsm[c*65];
  const float* Y2b = YQ + ((size_t)(b*4)<<12);
  const float* yb = ybar + (b<<6);
  float q=0.f, sbp=0.f;
  for (int m=qm*16; m<qm*16+16; m++){
    const float* row = Y2b + (m<<6);
    float ym=0.f;
    for (int nn=0;nn<64;nn+=4){
      float4 a0=*(const float4*)(row+nn);
      float4 a1=*(const float4*)(row+4096+nn);
      float4 a2=*(const float4*)(row+8192+nn);
      float4 a3=*(const float4*)(row+12288+nn);
      float sx=a0.x+a1.x+a2.x+a3.x;
      float sy=a0.y+a1.y+a2.y+a3.y;
      float sz=a0.z+a1.z+a2.z+a3.z;
      float sw=a0.w+a1.w+a2.w+a3.w;
      ym += sx*wv[nn] + sy*wv[nn+1] + sz*wv[nn+2] + sw*wv[nn+3];
    }
    q += ym*wv[m];
    sbp += wv[m]*yb[m];
  }
  float bias = eb[(g<<6)+c];
  float pz  = sbp + (qm==0 ? 16384.f*bias : 0.f);
  float pz2 = q + 2.f*bias*sbp + (qm==0 ? 16384.f*bias*bias : 0.f);
  red[t]=pz; red[256+t]=pz2;
  __syncthreads();
  for (int s=128;s>0;s>>=1){
    if (t<s){ red[t]+=red[t+s]; red[256+t]+=red[256+t+s]; }
    __syncthreads();
  }
  if (t==0){
    const float N=64.f*16384.f;
    float mu = red[0]/N;
    float var = red[256]/N - mu*mu;
    stats[bg*2]=mu; stats[bg*2+1]=rsqrtf(var+1e-5f);
  }
}

// ---- final MFMA: z = expand(y_bf16), GN apply + gelu + residual -> NCHW.
// 64-px tiles (grid 256x8), 8 KB LDS; depth-1 feat prefetch across nt loop;
// nontemporal stores for out (pure stream).
__global__ __launch_bounds__(256) void k_final(const ushort* __restrict__ y,
    const ushort* __restrict__ ewb, const float* __restrict__ eb,
    const float* __restrict__ stats, const float* __restrict__ gamma,
    const float* __restrict__ beta, const float* __restrict__ feat,
    float* __restrict__ out){
  __shared__ ushort A[64*64];            // 8 KB bf16 y-tile
  int t = threadIdx.x;
  int b = blockIdx.y, p0 = blockIdx.x*64;
  int lane = t & 63, w = t >> 6, ln = lane & 15, qd = lane >> 4;
  {
    int px = t>>2, ch0 = (t&3)*16;       // 16 ch = 32 B per thread
    const uint4* yp = (const uint4*)(y + ((size_t)(b*HW + p0 + px))*64 + ch0);
    uint4 v0 = yp[0], v1 = yp[1];
    int c16 = ch0 >> 3;                  // 16B-chunk index
    char* Ab = (char*)A + px*128;
    *(uint4*)(Ab + ((c16  )^(px&7))*16) = v0;
    *(uint4*)(Ab + ((c16+1)^(px&7))*16) = v1;
  }
  __syncthreads();
  float mu = stats[((b<<2)+w)*2], rstd = stats[((b<<2)+w)*2+1];
  const float* fb = feat + (size_t)b*CC*HW + p0;
  float* ob = out + (size_t)b*CC*HW + p0;
  // prefetch feat rows for nt=0
  f32x4 fpre[4];
  {
    const float* frow = fb + (size_t)((w<<6) + ln)*HW;
    #pragma unroll
    for (int pt=0;pt<4;pt++)
      fpre[pt] = *(const f32x4*)(frow + (pt<<4) + (qd<<2));
  }
  #pragma unroll
  for (int nt=0;nt<4;nt++){
    int nch = (w<<6) + (nt<<4) + ln;
    const ushort* wb = ewb + (size_t)nch*64 + (qd<<3);
    bf16x8 b0 = *(const bf16x8*)wb;
    bf16x8 b1 = *(const bf16x8*)(wb + 32);
    f32x4 acc[4];
    #pragma unroll
    for (int pt=0;pt<4;pt++) acc[pt] = (f32x4){0.f,0.f,0.f,0.f};
    #pragma unroll
    for (int pt=0;pt<4;pt++){
      int m = (pt<<4) + ln;
      int ch0 = qd ^ (m&7), ch1 = (4+qd) ^ (m&7);
      bf16x8 a0 = *(bf16x8*)(A + (m<<6) + (ch0<<3));
      acc[pt] = __builtin_amdgcn_mfma_f32_16x16x32_bf16(a0, b0, acc[pt], 0,0,0);
      bf16x8 a1 = *(bf16x8*)(A + (m<<6) + (ch1<<3));
      acc[pt] = __builtin_amdgcn_mfma_f32_16x16x32_bf16(a1, b1, acc[pt], 0,0,0);
    }
    // grab current feat, then issue next iteration's prefetch so the loads
    // are in flight during the 16-erff gelu phase below
    f32x4 fcur[4];
    #pragma unroll
    for (int pt=0;pt<4;pt++) fcur[pt] = fpre[pt];
    if (nt < 3){
      const float* frow = fb + (size_t)(nch + 16)*HW;
      #pragma unroll
      for (int pt=0;pt<4;pt++)
        fpre[pt] = *(const f32x4*)(frow + (pt<<4) + (qd<<2));
    }
    float bias = eb[nch];
    float ga = gamma[nch], be = beta[nch];
    float gr = rstd*ga;
    float ofs = (bias - mu)*gr + be;     // z*gr + ofs == (z+bias-mu)*rstd*ga + be
    float* orow = ob + (size_t)nch*HW;
    #pragma unroll
    for (int pt=0;pt<4;pt++){
      int px = (pt<<4) + (qd<<2);
      f32x4 f = fcur[pt];
      f32x4 o;
      o[0] = f[0] + gelu_f(acc[pt][0]*gr + ofs);
      o[1] = f[1] + gelu_f(acc[pt][1]*gr + ofs);
      o[2] = f[2] + gelu_f(acc[pt][2]*gr + ofs);
      o[3] = f[3] + gelu_f(acc[pt][3]*gr + ofs);
      __builtin_nontemporal_store(o, (f32x4*)(orow + px));
    }
  }
}

extern "C" void kernel_launch(void* const* d_in, const int* in_sizes, int n_in,
                              void* d_out, int out_size, void* d_ws, size_t ws_size,
                              hipStream_t stream){
  const float* feat = (const float*)d_in[0];
  const float* wind = (const float*)d_in[1];
  const float* cw   = (const float*)d_in[2];
  const float* cb   = (const float*)d_in[3];
  const float* w1   = (const float*)d_in[4];
  const float* b1   = (const float*)d_in[5];
  const float* w2   = (const float*)d_in[6];
  const float* b2   = (const float*)d_in[7];
  const float* dw   = (const float*)d_in[8];
  const float* db   = (const float*)d_in[9];
  const float* ew   = (const float*)d_in[10];
  const float* ebias= (const float*)d_in[11];
  const float* gg   = (const float*)d_in[12];
  const float* gb   = (const float*)d_in[13];
  float* ws = (float*)d_ws;
  float* x_nhwc   = ws;                    // 8388608 floats
  ushort* y_bf16  = (ushort*)(ws + 8388608);  // 8388608 ushorts (16.7 MB)
  float* h_nhwc   = ws + 16777216;         // 4194304 (reused as partY2 after off2)
  float* off_nhwc = ws + 20971520;         // 2359296 (reused: partYb + YQ after deform)
  ushort* bt      = (ushort*)(ws + 23330816); // 36864 ush
  ushort* cwb     = (ushort*)(ws + 23349248); // 16384 ush
  ushort* ewb     = (ushort*)(ws + 23357440); // 16384 ush
  float* ybar     = ws + 23398400;         // 512
  float* stats    = ws + 23398912;         // 64
  float* partY2   = h_nhwc;                // 1024*4096 floats, dead after off2
  float* partYb   = off_nhwc;              // 1024*64 floats, dead after deform's offs read
  float* YQ       = off_nhwc + 131072;     // 4*4096*8 floats (quarter-partial Y2)
  k_prep<<<272,256,0,stream>>>(dw, cw, ew, bt, cwb, ewb);
  k_compress<<<dim3(128,8),256,0,stream>>>(feat, cwb, cb, x_nhwc);
  k_off1<<<dim3(64,8),256,0,stream>>>(wind, w1, b1, h_nhwc);
  k_off2<<<dim3(64,8),256,0,stream>>>(h_nhwc, w2, b2, off_nhwc);
  k_deform<<<1024,256,0,stream>>>(x_nhwc, off_nhwc, bt, db, y_bf16, partY2, partYb);
  k_reduce<<<dim3(17,8),256,0,stream>>>(partY2, partYb, YQ, ybar);
  k_gn<<<32,256,0,stream>>>(YQ, ybar, ew, ebias, stats);
  k_final<<<dim3(256,8),256,0,stream>>>(y_bf16, ewb, ebias, stats, gg, gb, feat, (float*)d_out);
}